// Round 12
// baseline (261.676 us; speedup 1.0000x reference)
//
#include <hip/hip_runtime.h>
#include <hip/hip_bf16.h>

typedef __attribute__((ext_vector_type(4))) float f32x4;
typedef __attribute__((ext_vector_type(8))) __bf16 bf16x8;
typedef __attribute__((ext_vector_type(4))) __bf16 bf16x4;
typedef __attribute__((ext_vector_type(4))) unsigned int u32x4;
typedef unsigned long long u64;
typedef unsigned int u32;

#define DIMQ 512
#define NSEQ 4096
#define NHEAD 16
#define HDIM 32
#define SCALE_QK 0.17677669529663687f
#define C2F (SCALE_QK * 1.4426950408889634f)  // scale * log2(e), folded into Q

__device__ __forceinline__ void gload16(void* lds, const void* g) {
  __builtin_amdgcn_global_load_lds(
      (const __attribute__((address_space(1))) void*)g,
      (__attribute__((address_space(3))) void*)lds, 16, 0, 0);
}

// ---------------- conversion kernels ----------------

__global__ __launch_bounds__(256) void k_cvt_bf16(const float* __restrict__ in,
                                                  __bf16* __restrict__ out) {
  int i = blockIdx.x * 256 + threadIdx.x;
  float4 v = reinterpret_cast<const float4*>(in)[i];
  bf16x4 o;
  o.x = (__bf16)v.x; o.y = (__bf16)v.y; o.z = (__bf16)v.z; o.w = (__bf16)v.w;
  reinterpret_cast<bf16x4*>(out)[i] = o;
}

// in: fp32 [512][Nc]  ->  out: bf16 [Nc][512]  (transpose via LDS tile)
__global__ __launch_bounds__(256) void k_cvtT(const float* __restrict__ in,
                                              __bf16* __restrict__ out, int Nc) {
  __shared__ __bf16 t[64][72];
  int k0 = blockIdx.y * 64, n0 = blockIdx.x * 64;
  int c = threadIdx.x & 63, rr = threadIdx.x >> 6;
#pragma unroll
  for (int i = 0; i < 16; ++i) {
    int r = rr * 16 + i;
    t[r][c] = (__bf16)in[(size_t)(k0 + r) * Nc + n0 + c];
  }
  __syncthreads();
#pragma unroll
  for (int i = 0; i < 16; ++i) {
    int r = rr * 16 + i;
    out[(size_t)(n0 + r) * 512 + k0 + c] = t[c][r];
  }
}

// int32 mask [4096][4096] -> PERMUTED bit mask [4096][64] u64.
// Lane l ballots column kvp(l) so the two mask bits of each packed-bf16 pair
// (pa elements 2w,2w+1) sit 16 bits apart:
//   mt bit l  <->  kv = 32*l5 | 16*l1 | (l3:2)*4 | 2*l0 | l4
__global__ __launch_bounds__(256) void k_maskbits(const int* __restrict__ mask,
                                                  u64* __restrict__ bits) {
  int row = blockIdx.x;
  int l = threadIdx.x & 63, w = threadIdx.x >> 6;
  const int jj = l >> 5, odd = (l >> 4) & 1, gg = (l >> 2) & 3, wb = l & 3;
  const int kvp = 32 * jj + 16 * (wb >> 1) + 4 * gg + 2 * (wb & 1) + odd;
  const int* mr = mask + (size_t)row * NSEQ;
  for (int t = w; t < 64; t += 4) {
    u64 b = __ballot(mr[t * 64 + kvp] != 0);
    if (l == 0) bits[(size_t)row * 64 + t] = b;
  }
}

// ---------------- shared GEMM main loop (m97-style, swizzled gload_lds) ----------------
__device__ __forceinline__ void gemm_mainloop(const __bf16* __restrict__ A,
                                              const __bf16* __restrict__ Bt,
                                              int m0, int n0,
                                              __bf16* As, __bf16* Bs,
                                              f32x4 acc[4][4]) {
  const int tid = threadIdx.x, l = tid & 63, w = tid >> 6;
  const int wr = w >> 1, wc = w & 1;
  for (int kt = 0; kt < DIMQ; kt += 64) {
    __syncthreads();
#pragma unroll
    for (int it = 0; it < 4; ++it) {
      int c = it * 256 + tid;
      int row = c >> 3, j = c & 7, js = j ^ (row & 7);
      gload16(As + (size_t)(it * 256 + w * 64) * 8,
              A + (size_t)(m0 + row) * DIMQ + kt + js * 8);
      gload16(Bs + (size_t)(it * 256 + w * 64) * 8,
              Bt + (size_t)(n0 + row) * DIMQ + kt + js * 8);
    }
    __syncthreads();
#pragma unroll
    for (int kk = 0; kk < 2; ++kk) {
      bf16x8 a[4], b[4];
#pragma unroll
      for (int mt = 0; mt < 4; ++mt) {
        int row = wr * 64 + mt * 16 + (l & 15);
        int g = (kk * 4 + (l >> 4)) ^ (row & 7);
        a[mt] = *reinterpret_cast<const bf16x8*>((const char*)As + row * 128 + g * 16);
      }
#pragma unroll
      for (int nt = 0; nt < 4; ++nt) {
        int row = wc * 64 + nt * 16 + (l & 15);
        int g = (kk * 4 + (l >> 4)) ^ (row & 7);
        b[nt] = *reinterpret_cast<const bf16x8*>((const char*)Bs + row * 128 + g * 16);
      }
#pragma unroll
      for (int mt = 0; mt < 4; ++mt)
#pragma unroll
        for (int nt = 0; nt < 4; ++nt)
          acc[mt][nt] = __builtin_amdgcn_mfma_f32_16x16x32_bf16(a[mt], b[nt], acc[mt][nt], 0, 0, 0);
    }
  }
}

// ---------------- QKV GEMM (epilogue: head layout; Q pre-scaled; V transposed + k-permuted) ----------------
__global__ __launch_bounds__(256) void k_gemm_qkv(const __bf16* __restrict__ A,
                                                  const __bf16* __restrict__ Bt,
                                                  __bf16* __restrict__ Qh,
                                                  __bf16* __restrict__ Kh,
                                                  __bf16* __restrict__ VT) {
  __shared__ __bf16 As[128 * 64], Bs[128 * 64];
  f32x4 acc[4][4] = {};
  const int l = threadIdx.x & 63, w = threadIdx.x >> 6, wr = w >> 1, wc = w & 1;
  const int m0 = blockIdx.y * 128, n0 = blockIdx.x * 128;
  gemm_mainloop(A, Bt, m0, n0, As, Bs, acc);
#pragma unroll
  for (int nt = 0; nt < 4; ++nt) {
    int n = n0 + wc * 64 + nt * 16 + (l & 15);
    int sec = n >> 9;           // 0=q 1=k 2=v
    int hh = (n >> 5) & 15;     // head
    int d = n & 31;             // dim in head
#pragma unroll
    for (int mt = 0; mt < 4; ++mt) {
      int m = m0 + wr * 64 + mt * 16 + (l >> 4) * 4;
      int bb = m >> 12, nn = m & 4095;
      size_t bh = (size_t)bb * NHEAD + hh;
      f32x4 v = acc[mt][nt];
      if (sec == 0) {
        __bf16* p = Qh + (bh * NSEQ + nn) * HDIM + d;
        p[0] = (__bf16)(v[0] * C2F); p[HDIM] = (__bf16)(v[1] * C2F);
        p[2 * HDIM] = (__bf16)(v[2] * C2F); p[3 * HDIM] = (__bf16)(v[3] * C2F);
      } else if (sec == 1) {
        __bf16* p = Kh + (bh * NSEQ + nn) * HDIM + d;
        p[0] = (__bf16)v[0]; p[HDIM] = (__bf16)v[1];
        p[2 * HDIM] = (__bf16)v[2]; p[3 * HDIM] = (__bf16)v[3];
      } else {
        // k-permuted V: within each 32-kv group, low5 = hi*16 + g*4 + r -> g*8 + hi*4 + r
        // (nn % 4 == 0, so r = 0 for the vector base)
        int low = nn & 31;
        int nnp = (nn & ~31) | (((low >> 2) & 3) << 3) | (((low >> 4) & 1) << 2);
        bf16x4 o;
        o.x = (__bf16)v[0]; o.y = (__bf16)v[1]; o.z = (__bf16)v[2]; o.w = (__bf16)v[3];
        *reinterpret_cast<bf16x4*>(VT + (bh * HDIM + d) * NSEQ + nnp) = o;
      }
    }
  }
}

// ---------------- fused masked attention, v9 ----------------
// grid 1024 (XCD decode), 512 thr = 8 waves x 16 q-rows = 128 q-rows/block.
// Target 4 blocks/CU = 32 waves/CU (8/SIMD) for latency hiding: 16 KB LDS
// (2-slot double buffer), <=64 VGPR via __launch_bounds__(512,8).
// Staging: waves 0-3 stage K, waves 4-7 stage V -> ONE gload16/thread/tile.
// Per-wave tile: swapped QK^T, no-max exp2, packed-AND mask (permuted ballot),
// single-b128 permuted V, row-sums via MFMA vs ones.
__device__ __forceinline__ void attn_compute(const __bf16* __restrict__ Kl,
                                             const __bf16* __restrict__ Vl,
                                             bf16x8 qf, u64 mw,
                                             f32x4 acc[2], f32x4& accS,
                                             int kOff, const int vOff[2][2],
                                             bf16x8 ones, int g) {
  bf16x8 kf[4];
#pragma unroll
  for (int f = 0; f < 4; ++f)
    kf[f] = *reinterpret_cast<const bf16x8*>(Kl + kOff + f * 512);

  bf16x8 vvb[2][2];  // [jj][dt], single b128 each
#pragma unroll
  for (int jj = 0; jj < 2; ++jj)
#pragma unroll
    for (int dt = 0; dt < 2; ++dt)
      vvb[jj][dt] = *reinterpret_cast<const bf16x8*>(Vl + vOff[jj][dt]);

  const f32x4 z4 = {0.f, 0.f, 0.f, 0.f};
  f32x4 s0 = __builtin_amdgcn_mfma_f32_16x16x32_bf16(kf[0], qf, z4, 0, 0, 0);
  f32x4 s1 = __builtin_amdgcn_mfma_f32_16x16x32_bf16(kf[1], qf, z4, 0, 0, 0);
  f32x4 s2 = __builtin_amdgcn_mfma_f32_16x16x32_bf16(kf[2], qf, z4, 0, 0, 0);
  f32x4 s3 = __builtin_amdgcn_mfma_f32_16x16x32_bf16(kf[3], qf, z4, 0, 0, 0);

#pragma unroll
  for (int jj = 0; jj < 2; ++jj) {
    const f32x4 sa = jj ? s2 : s0;
    const f32x4 sb = jj ? s3 : s1;
    bf16x8 pa;  // k order e = hi*4 + r matches permuted-V b128 order
#pragma unroll
    for (int r = 0; r < 4; ++r) {
      pa[r] = (__bf16)__builtin_exp2f(sa[r]);
      pa[r + 4] = (__bf16)__builtin_exp2f(sb[r]);
    }
    const u32 x = ((u32)(mw >> (32 * jj))) >> (g * 4);
    u32x4 pw = __builtin_bit_cast(u32x4, pa);
#pragma unroll
    for (int wq = 0; wq < 4; ++wq) {
      u32 zb = (x >> wq) & 0x10001u;
      pw[wq] &= (zb << 16) - zb;  // 0 / 0xFFFF / 0xFFFF0000 / 0xFFFFFFFF
    }
    bf16x8 pm = __builtin_bit_cast(bf16x8, pw);
    accS = __builtin_amdgcn_mfma_f32_16x16x32_bf16(pm, ones, accS, 0, 0, 0);
    acc[0] = __builtin_amdgcn_mfma_f32_16x16x32_bf16(pm, vvb[jj][0], acc[0], 0, 0, 0);
    acc[1] = __builtin_amdgcn_mfma_f32_16x16x32_bf16(pm, vvb[jj][1], acc[1], 0, 0, 0);
  }
}

__global__ __launch_bounds__(512, 8) void k_attn(const __bf16* __restrict__ Qh,
                                                 const __bf16* __restrict__ Kh,
                                                 const __bf16* __restrict__ VT,
                                                 const u64* __restrict__ mbits,
                                                 __bf16* __restrict__ O) {
  __shared__ __bf16 Klds[2][2048];  // [64 rows][4 slots x 16B], slot-swizzled
  __shared__ __bf16 Vlds[2][2048];  // [32 d][8 granules x 16B], granule-swizzled
  const int tid = threadIdx.x;
  const int l = tid & 63, w = tid >> 6;          // w: 0..7
  const int g = l >> 4, q16 = l & 15;
  const int bid = blockIdx.x;
  const int bh = (bid & 7) * 4 + ((bid >> 3) & 3);  // XCD-aware decode
  const int qx = bid >> 5;                          // 0..31
  const int q0 = qx * 128 + w * 16;
  const __bf16* Qb = Qh + (size_t)bh * NSEQ * HDIM;
  const __bf16* Kb = Kh + (size_t)bh * NSEQ * HDIM;
  const __bf16* Vb = VT + (size_t)bh * HDIM * NSEQ;  // [32 d][4096 kp]
  const u64* mr = mbits + (size_t)(q0 + q16) * 64;

  // staging sources: waves 0-3 stage K (4KB), waves 4-7 stage V (4KB).
  // pre-swizzled source so linear LDS dest + swizzled read match.
  const __bf16* srcS;
  __bf16* ldsS0;
  __bf16* ldsS1;
  if (tid < 256) {
    const int rk = tid >> 2, gsK = (tid & 3) ^ ((rk >> 1) & 3);
    srcS = Kb + (size_t)rk * HDIM + gsK * 8;         // += t*2048
    ldsS0 = &Klds[0][0] + tid * 8;
    ldsS1 = &Klds[1][0] + tid * 8;
  } else {
    const int tv = tid - 256;
    const int dv = tv >> 3, gv = (tv & 7) ^ (dv & 7);
    srcS = Vb + (size_t)dv * NSEQ + gv * 8;          // += t*64 (kv stride)
    ldsS0 = &Vlds[0][0] + tv * 8;
    ldsS1 = &Vlds[1][0] + tv * 8;
  }
  const size_t srcStride = (tid < 256) ? 2048 : 64;  // elems per kv tile

  // LDS read offsets (loop-invariant, elements)
  const int kOff = q16 * 32 + (g ^ ((q16 >> 1) & 3)) * 8;
  int vOff[2][2];
#pragma unroll
  for (int jj = 0; jj < 2; ++jj)
#pragma unroll
    for (int dt = 0; dt < 2; ++dt) {
      int d = dt * 16 + q16;
      vOff[jj][dt] = d * 64 + ((4 * jj + g) ^ (d & 7)) * 8;
    }

  bf16x8 qf = *reinterpret_cast<const bf16x8*>(
      Qb + (size_t)(q0 + q16) * HDIM + g * 8);

  bf16x8 ones;
#pragma unroll
  for (int e = 0; e < 8; ++e) ones[e] = (__bf16)1.0f;

  f32x4 acc[2] = {};
  f32x4 accS = {};

  // prologue: stage tile 0 into buf0
  gload16(ldsS0, srcS);
  u64 a0 = mr[0], b0;
  __syncthreads();

  for (int t = 0; t < 64; t += 2) {
    // phase A: stage t+1 -> buf1, compute t from buf0
    gload16(ldsS1, srcS + (size_t)(t + 1) * srcStride);
    b0 = mr[t + 1];
    attn_compute(&Klds[0][0], &Vlds[0][0], qf, a0, acc, accS, kOff, vOff, ones, g);
    __syncthreads();
    // phase B: stage t+2 -> buf0 (clamped), compute t+1 from buf1
    const int t2 = (t + 2 < 64) ? t + 2 : 63;
    gload16(ldsS0, srcS + (size_t)t2 * srcStride);
    a0 = mr[t2];
    attn_compute(&Klds[1][0], &Vlds[1][0], qf, b0, acc, accS, kOff, vOff, ones, g);
    __syncthreads();
  }

  const int bb = bh >> 4, hh = bh & 15;
#pragma unroll
  for (int r = 0; r < 4; ++r) {
    float inv = 1.f / accS[r];  // denominator in same lane/reg as numerator
    int qrow = q0 + g * 4 + r;
#pragma unroll
    for (int dt = 0; dt < 2; ++dt)
      O[((size_t)bb * NSEQ + qrow) * DIMQ + hh * HDIM + dt * 16 + q16] =
          (__bf16)(acc[dt][r] * inv);
  }
}

// ---------------- output projection GEMM (fp32 output) ----------------
__global__ __launch_bounds__(256) void k_gemm_proj(const __bf16* __restrict__ A,
                                                   const __bf16* __restrict__ Bt,
                                                   float* __restrict__ Out) {
  __shared__ __bf16 As[128 * 64], Bs[128 * 64];
  f32x4 acc[4][4] = {};
  const int l = threadIdx.x & 63, w = threadIdx.x >> 6, wr = w >> 1, wc = w & 1;
  const int m0 = blockIdx.y * 128, n0 = blockIdx.x * 128;
  gemm_mainloop(A, Bt, m0, n0, As, Bs, acc);
#pragma unroll
  for (int nt = 0; nt < 4; ++nt) {
    int n = n0 + wc * 64 + nt * 16 + (l & 15);
#pragma unroll
    for (int mt = 0; mt < 4; ++mt) {
      int m = m0 + wr * 64 + mt * 16 + (l >> 4) * 4;
      f32x4 v = acc[mt][nt];
      float* p = Out + (size_t)m * DIMQ + n;
      p[0] = v[0]; p[DIMQ] = v[1];
      p[2 * DIMQ] = v[2]; p[3 * DIMQ] = v[3];
    }
  }
}

// ---------------- launcher ----------------
extern "C" void kernel_launch(void* const* d_in, const int* in_sizes, int n_in,
                              void* d_out, int out_size, void* d_ws, size_t ws_size,
                              hipStream_t stream) {
  (void)in_sizes; (void)n_in; (void)out_size; (void)ws_size;
  const float* batch  = (const float*)d_in[0];
  const float* w_qkv  = (const float*)d_in[1];
  const float* w_proj = (const float*)d_in[2];
  const int*   cmask  = (const int*)d_in[3];

  __bf16* Abf = (__bf16*)d_ws;                       // 8192*512 bf16
  __bf16* WqT = Abf + (size_t)8192 * 512;            // 1536*512
  __bf16* WpT = WqT + (size_t)1536 * 512;            // 512*512
  u64*    mb  = (u64*)(WpT + (size_t)512 * 512);     // 4096*64 u64
  __bf16* Qh  = (__bf16*)(mb + (size_t)4096 * 64);   // 32*4096*32
  __bf16* Kh  = Qh + (size_t)32 * NSEQ * HDIM;
  __bf16* VT  = Kh + (size_t)32 * NSEQ * HDIM;
  __bf16* Obf = VT + (size_t)32 * NSEQ * HDIM;       // 8192*512

  k_cvt_bf16<<<4096, 256, 0, stream>>>(batch, Abf);
  k_cvtT<<<dim3(24, 8), 256, 0, stream>>>(w_qkv, WqT, 1536);
  k_cvtT<<<dim3(8, 8), 256, 0, stream>>>(w_proj, WpT, 512);
  k_maskbits<<<4096, 256, 0, stream>>>(cmask, mb);
  k_gemm_qkv<<<dim3(12, 64), 256, 0, stream>>>(Abf, WqT, Qh, Kh, VT);
  k_attn<<<1024, 512, 0, stream>>>(Qh, Kh, VT, mb, Obf);
  k_gemm_proj<<<dim3(4, 64), 256, 0, stream>>>(Obf, WpT, (float*)d_out);
}

// Round 13
// 246.444 us; speedup vs baseline: 1.0618x; 1.0618x over previous
//
#include <hip/hip_runtime.h>
#include <hip/hip_bf16.h>

typedef __attribute__((ext_vector_type(4))) float f32x4;
typedef __attribute__((ext_vector_type(8))) __bf16 bf16x8;
typedef __attribute__((ext_vector_type(4))) __bf16 bf16x4;
typedef __attribute__((ext_vector_type(4))) unsigned int u32x4;
typedef unsigned long long u64;
typedef unsigned int u32;

#define DIMQ 512
#define NSEQ 4096
#define NHEAD 16
#define HDIM 32
#define SCALE_QK 0.17677669529663687f
#define C2F (SCALE_QK * 1.4426950408889634f)  // scale * log2(e), folded into Q

__device__ __forceinline__ void gload16(void* lds, const void* g) {
  __builtin_amdgcn_global_load_lds(
      (const __attribute__((address_space(1))) void*)g,
      (__attribute__((address_space(3))) void*)lds, 16, 0, 0);
}

// ---------------- conversion kernels ----------------

__global__ __launch_bounds__(256) void k_cvt_bf16(const float* __restrict__ in,
                                                  __bf16* __restrict__ out) {
  int i = blockIdx.x * 256 + threadIdx.x;
  float4 v = reinterpret_cast<const float4*>(in)[i];
  bf16x4 o;
  o.x = (__bf16)v.x; o.y = (__bf16)v.y; o.z = (__bf16)v.z; o.w = (__bf16)v.w;
  reinterpret_cast<bf16x4*>(out)[i] = o;
}

// in: fp32 [512][Nc]  ->  out: bf16 [Nc][512]  (transpose via LDS tile)
__global__ __launch_bounds__(256) void k_cvtT(const float* __restrict__ in,
                                              __bf16* __restrict__ out, int Nc) {
  __shared__ __bf16 t[64][72];
  int k0 = blockIdx.y * 64, n0 = blockIdx.x * 64;
  int c = threadIdx.x & 63, rr = threadIdx.x >> 6;
#pragma unroll
  for (int i = 0; i < 16; ++i) {
    int r = rr * 16 + i;
    t[r][c] = (__bf16)in[(size_t)(k0 + r) * Nc + n0 + c];
  }
  __syncthreads();
#pragma unroll
  for (int i = 0; i < 16; ++i) {
    int r = rr * 16 + i;
    out[(size_t)(n0 + r) * 512 + k0 + c] = t[c][r];
  }
}

// int32 mask [4096][4096] -> PERMUTED bit mask [4096][64] u64.
// Lane l ballots column kvp(l) so the two mask bits of each packed-bf16 pair
// (pa elements 2w,2w+1) sit 16 bits apart:
//   mt bit l  <->  kv = 32*l5 | 16*l1 | (l3:2)*4 | 2*l0 | l4
__global__ __launch_bounds__(256) void k_maskbits(const int* __restrict__ mask,
                                                  u64* __restrict__ bits) {
  int row = blockIdx.x;
  int l = threadIdx.x & 63, w = threadIdx.x >> 6;
  const int jj = l >> 5, odd = (l >> 4) & 1, gg = (l >> 2) & 3, wb = l & 3;
  const int kvp = 32 * jj + 16 * (wb >> 1) + 4 * gg + 2 * (wb & 1) + odd;
  const int* mr = mask + (size_t)row * NSEQ;
  for (int t = w; t < 64; t += 4) {
    u64 b = __ballot(mr[t * 64 + kvp] != 0);
    if (l == 0) bits[(size_t)row * 64 + t] = b;
  }
}

// ---------------- shared GEMM main loop (m97-style, swizzled gload_lds) ----------------
__device__ __forceinline__ void gemm_mainloop(const __bf16* __restrict__ A,
                                              const __bf16* __restrict__ Bt,
                                              int m0, int n0,
                                              __bf16* As, __bf16* Bs,
                                              f32x4 acc[4][4]) {
  const int tid = threadIdx.x, l = tid & 63, w = tid >> 6;
  const int wr = w >> 1, wc = w & 1;
  for (int kt = 0; kt < DIMQ; kt += 64) {
    __syncthreads();
#pragma unroll
    for (int it = 0; it < 4; ++it) {
      int c = it * 256 + tid;
      int row = c >> 3, j = c & 7, js = j ^ (row & 7);
      gload16(As + (size_t)(it * 256 + w * 64) * 8,
              A + (size_t)(m0 + row) * DIMQ + kt + js * 8);
      gload16(Bs + (size_t)(it * 256 + w * 64) * 8,
              Bt + (size_t)(n0 + row) * DIMQ + kt + js * 8);
    }
    __syncthreads();
#pragma unroll
    for (int kk = 0; kk < 2; ++kk) {
      bf16x8 a[4], b[4];
#pragma unroll
      for (int mt = 0; mt < 4; ++mt) {
        int row = wr * 64 + mt * 16 + (l & 15);
        int g = (kk * 4 + (l >> 4)) ^ (row & 7);
        a[mt] = *reinterpret_cast<const bf16x8*>((const char*)As + row * 128 + g * 16);
      }
#pragma unroll
      for (int nt = 0; nt < 4; ++nt) {
        int row = wc * 64 + nt * 16 + (l & 15);
        int g = (kk * 4 + (l >> 4)) ^ (row & 7);
        b[nt] = *reinterpret_cast<const bf16x8*>((const char*)Bs + row * 128 + g * 16);
      }
#pragma unroll
      for (int mt = 0; mt < 4; ++mt)
#pragma unroll
        for (int nt = 0; nt < 4; ++nt)
          acc[mt][nt] = __builtin_amdgcn_mfma_f32_16x16x32_bf16(a[mt], b[nt], acc[mt][nt], 0, 0, 0);
    }
  }
}

// ---------------- QKV GEMM (epilogue: head layout; Q pre-scaled; V transposed + k-permuted) ----------------
__global__ __launch_bounds__(256) void k_gemm_qkv(const __bf16* __restrict__ A,
                                                  const __bf16* __restrict__ Bt,
                                                  __bf16* __restrict__ Qh,
                                                  __bf16* __restrict__ Kh,
                                                  __bf16* __restrict__ VT) {
  __shared__ __bf16 As[128 * 64], Bs[128 * 64];
  f32x4 acc[4][4] = {};
  const int l = threadIdx.x & 63, w = threadIdx.x >> 6, wr = w >> 1, wc = w & 1;
  const int m0 = blockIdx.y * 128, n0 = blockIdx.x * 128;
  gemm_mainloop(A, Bt, m0, n0, As, Bs, acc);
#pragma unroll
  for (int nt = 0; nt < 4; ++nt) {
    int n = n0 + wc * 64 + nt * 16 + (l & 15);
    int sec = n >> 9;           // 0=q 1=k 2=v
    int hh = (n >> 5) & 15;     // head
    int d = n & 31;             // dim in head
#pragma unroll
    for (int mt = 0; mt < 4; ++mt) {
      int m = m0 + wr * 64 + mt * 16 + (l >> 4) * 4;
      int bb = m >> 12, nn = m & 4095;
      size_t bh = (size_t)bb * NHEAD + hh;
      f32x4 v = acc[mt][nt];
      if (sec == 0) {
        __bf16* p = Qh + (bh * NSEQ + nn) * HDIM + d;
        p[0] = (__bf16)(v[0] * C2F); p[HDIM] = (__bf16)(v[1] * C2F);
        p[2 * HDIM] = (__bf16)(v[2] * C2F); p[3 * HDIM] = (__bf16)(v[3] * C2F);
      } else if (sec == 1) {
        __bf16* p = Kh + (bh * NSEQ + nn) * HDIM + d;
        p[0] = (__bf16)v[0]; p[HDIM] = (__bf16)v[1];
        p[2 * HDIM] = (__bf16)v[2]; p[3 * HDIM] = (__bf16)v[3];
      } else {
        // k-permuted V: within each 32-kv group, low5 = hi*16 + g*4 + r -> g*8 + hi*4 + r
        // (nn % 4 == 0, so r = 0 for the vector base)
        int low = nn & 31;
        int nnp = (nn & ~31) | (((low >> 2) & 3) << 3) | (((low >> 4) & 1) << 2);
        bf16x4 o;
        o.x = (__bf16)v[0]; o.y = (__bf16)v[1]; o.z = (__bf16)v[2]; o.w = (__bf16)v[3];
        *reinterpret_cast<bf16x4*>(VT + (bh * HDIM + d) * NSEQ + nnp) = o;
      }
    }
  }
}

// ---------------- fused masked attention, v10: v7 tile + kv-split x2 ----------------
// grid 2048: sp = bid>>10 selects kv half; rest decodes as v7 (XCD-aware; splits
// of the same bh share an XCD so L2 set is unchanged). 4 waves x 32 q-rows,
// 16KB double-buffered LDS, launch_bounds(256,4) (proven 52 VGPR, NO spill) ->
// 8 blocks/CU = 8 waves/SIMD resident. Blocks write unnormalized fp32 partial
// O + per-row denominator; k_combine normalizes.
__device__ __forceinline__ void attn_compute(const __bf16* __restrict__ Kl,
                                             const __bf16* __restrict__ Vl,
                                             const bf16x8 qf[2], u64 mw0, u64 mw1,
                                             f32x4 acc[2][2], f32x4 accS[2],
                                             int kOff, const int vOff[2][2],
                                             bf16x8 ones, int g) {
  bf16x8 kf[4];
#pragma unroll
  for (int f = 0; f < 4; ++f)
    kf[f] = *reinterpret_cast<const bf16x8*>(Kl + kOff + f * 512);

  bf16x8 vvb[2][2];  // [jj][dt], single b128 each
#pragma unroll
  for (int jj = 0; jj < 2; ++jj)
#pragma unroll
    for (int dt = 0; dt < 2; ++dt)
      vvb[jj][dt] = *reinterpret_cast<const bf16x8*>(Vl + vOff[jj][dt]);

  const f32x4 z4 = {0.f, 0.f, 0.f, 0.f};
#pragma unroll
  for (int rt = 0; rt < 2; ++rt) {
    const u64 mw = rt ? mw1 : mw0;
#pragma unroll
    for (int jj = 0; jj < 2; ++jj) {
      // S^T for kv halves f=2jj, 2jj+1: lane holds q=q16, k=16f+4g+r
      f32x4 s0 = __builtin_amdgcn_mfma_f32_16x16x32_bf16(kf[2 * jj], qf[rt], z4, 0, 0, 0);
      f32x4 s1 = __builtin_amdgcn_mfma_f32_16x16x32_bf16(kf[2 * jj + 1], qf[rt], z4, 0, 0, 0);
      bf16x8 pa;  // k order e = hi*4 + r matches permuted-V b128 order
#pragma unroll
      for (int r = 0; r < 4; ++r) {
        pa[r] = (__bf16)__builtin_exp2f(s0[r]);
        pa[r + 4] = (__bf16)__builtin_exp2f(s1[r]);
      }
      const u32 x = ((u32)(mw >> (32 * jj))) >> (g * 4);
      u32x4 pw = __builtin_bit_cast(u32x4, pa);
#pragma unroll
      for (int wq = 0; wq < 4; ++wq) {
        u32 zb = (x >> wq) & 0x10001u;
        pw[wq] &= (zb << 16) - zb;  // 0 / 0xFFFF / 0xFFFF0000 / 0xFFFFFFFF
      }
      bf16x8 pm = __builtin_bit_cast(bf16x8, pw);
      accS[rt] = __builtin_amdgcn_mfma_f32_16x16x32_bf16(pm, ones, accS[rt], 0, 0, 0);
#pragma unroll
      for (int dt = 0; dt < 2; ++dt)
        acc[rt][dt] =
            __builtin_amdgcn_mfma_f32_16x16x32_bf16(pm, vvb[jj][dt], acc[rt][dt], 0, 0, 0);
    }
  }
}

__global__ __launch_bounds__(256, 4) void k_attn(const __bf16* __restrict__ Qh,
                                                 const __bf16* __restrict__ Kh,
                                                 const __bf16* __restrict__ VT,
                                                 const u64* __restrict__ mbits,
                                                 float* __restrict__ Opart,
                                                 float* __restrict__ Lpart) {
  __shared__ __bf16 Klds[2][2048];  // [64 rows][4 slots x 16B], slot-swizzled
  __shared__ __bf16 Vlds[2][2048];  // [32 d][8 granules x 16B], granule-swizzled
  const int tid = threadIdx.x;
  const int l = tid & 63, w = tid >> 6;
  const int g = l >> 4, q16 = l & 15;
  const int bid = blockIdx.x;
  const int sp = bid >> 10;                          // kv split: 0 or 1
  const int rest = bid & 1023;
  const int bh = (rest & 7) * 4 + ((rest >> 3) & 3); // XCD-aware decode
  const int qx = rest >> 5;                          // 0..31
  const int q0 = qx * 128 + w * 32;
  const int base = sp * 32;                          // kv tile range [base, base+32)
  const __bf16* Qb = Qh + (size_t)bh * NSEQ * HDIM;
  const __bf16* Kb = Kh + (size_t)bh * NSEQ * HDIM;
  const __bf16* Vb = VT + (size_t)bh * HDIM * NSEQ;  // [32 d][4096 kp]
  const u64* mr0 = mbits + (size_t)(q0 + q16) * 64;
  const u64* mr1 = mbits + (size_t)(q0 + 16 + q16) * 64;

  // staging sources (pre-swizzled: linear LDS dest + swizzled read match)
  const int rk = tid >> 2, gsK = (tid & 3) ^ ((rk >> 1) & 3);
  const __bf16* srcK = Kb + (size_t)rk * HDIM + gsK * 8;   // += t*2048
  const int dv = tid >> 3, gv = (tid & 7) ^ (dv & 7);
  const __bf16* srcV = Vb + (size_t)dv * NSEQ + gv * 8;    // += t*64

  // LDS read offsets (loop-invariant, elements)
  const int kOff = q16 * 32 + (g ^ ((q16 >> 1) & 3)) * 8;
  int vOff[2][2];
#pragma unroll
  for (int jj = 0; jj < 2; ++jj)
#pragma unroll
    for (int dt = 0; dt < 2; ++dt) {
      int d = dt * 16 + q16;
      vOff[jj][dt] = d * 64 + ((4 * jj + g) ^ (d & 7)) * 8;
    }

  bf16x8 qf[2];
#pragma unroll
  for (int rt = 0; rt < 2; ++rt)
    qf[rt] = *reinterpret_cast<const bf16x8*>(
        Qb + (size_t)(q0 + rt * 16 + q16) * HDIM + g * 8);

  bf16x8 ones;
#pragma unroll
  for (int e = 0; e < 8; ++e) ones[e] = (__bf16)1.0f;

  f32x4 acc[2][2] = {};
  f32x4 accS[2] = {};

  // prologue: stage tile `base` into buf0, prefetch its mask words
  gload16(&Klds[0][0] + tid * 8, srcK + (size_t)base * 2048);
  gload16(&Vlds[0][0] + tid * 8, srcV + (size_t)base * 64);
  u64 a0 = mr0[base], a1 = mr1[base];
  u64 b0, b1;
  __syncthreads();

  for (int t = base; t < base + 32; t += 2) {
    // phase A: stage t+1 -> buf1, compute t from buf0
    gload16(&Klds[1][0] + tid * 8, srcK + (size_t)(t + 1) * 2048);
    gload16(&Vlds[1][0] + tid * 8, srcV + (size_t)(t + 1) * 64);
    b0 = mr0[t + 1]; b1 = mr1[t + 1];
    attn_compute(&Klds[0][0], &Vlds[0][0], qf, a0, a1, acc, accS, kOff, vOff, ones, g);
    __syncthreads();
    // phase B: stage t+2 -> buf0 (clamped), compute t+1 from buf1
    const int t2 = (t + 2 < base + 32) ? t + 2 : base + 31;
    gload16(&Klds[0][0] + tid * 8, srcK + (size_t)t2 * 2048);
    gload16(&Vlds[0][0] + tid * 8, srcV + (size_t)t2 * 64);
    a0 = mr0[t2]; a1 = mr1[t2];
    attn_compute(&Klds[1][0], &Vlds[1][0], qf, b0, b1, acc, accS, kOff, vOff, ones, g);
    __syncthreads();
  }

  const int bb = bh >> 4, hh = bh & 15;
  float* Op = Opart + (size_t)sp * 8192 * 512;
  float* Lp = Lpart + (size_t)sp * 32 * 4096;
#pragma unroll
  for (int rt = 0; rt < 2; ++rt)
#pragma unroll
    for (int r = 0; r < 4; ++r) {
      int qrow = q0 + rt * 16 + g * 4 + r;
      if (q16 == 0) Lp[(size_t)bh * 4096 + qrow] = accS[rt][r];
#pragma unroll
      for (int dt = 0; dt < 2; ++dt)
        Op[((size_t)bb * NSEQ + qrow) * DIMQ + hh * HDIM + dt * 16 + q16] =
            acc[rt][dt][r];
    }
}

// ---------------- split combine: Obf = (Op0+Op1) / (L0+L1) ----------------
__global__ __launch_bounds__(256) void k_combine(const float* __restrict__ Opart,
                                                 const float* __restrict__ Lpart,
                                                 __bf16* __restrict__ Obf) {
  const int i = blockIdx.x * 256 + threadIdx.x;  // handles 4 consecutive elems
  const size_t base = (size_t)i * 4;
  const int m = (int)(base >> 9), n = (int)(base & 511);
  const int bb = m >> 12, nn = m & 4095, hh = n >> 5;
  float4 a = *reinterpret_cast<const float4*>(Opart + base);
  float4 b = *reinterpret_cast<const float4*>(Opart + (size_t)8192 * 512 + base);
  const size_t li = ((size_t)(bb * 16 + hh)) * 4096 + nn;
  float inv = 1.f / (Lpart[li] + Lpart[(size_t)32 * 4096 + li]);
  bf16x4 o;
  o.x = (__bf16)((a.x + b.x) * inv);
  o.y = (__bf16)((a.y + b.y) * inv);
  o.z = (__bf16)((a.z + b.z) * inv);
  o.w = (__bf16)((a.w + b.w) * inv);
  *reinterpret_cast<bf16x4*>(Obf + base) = o;
}

// ---------------- output projection GEMM (fp32 output) ----------------
__global__ __launch_bounds__(256) void k_gemm_proj(const __bf16* __restrict__ A,
                                                   const __bf16* __restrict__ Bt,
                                                   float* __restrict__ Out) {
  __shared__ __bf16 As[128 * 64], Bs[128 * 64];
  f32x4 acc[4][4] = {};
  const int l = threadIdx.x & 63, w = threadIdx.x >> 6, wr = w >> 1, wc = w & 1;
  const int m0 = blockIdx.y * 128, n0 = blockIdx.x * 128;
  gemm_mainloop(A, Bt, m0, n0, As, Bs, acc);
#pragma unroll
  for (int nt = 0; nt < 4; ++nt) {
    int n = n0 + wc * 64 + nt * 16 + (l & 15);
#pragma unroll
    for (int mt = 0; mt < 4; ++mt) {
      int m = m0 + wr * 64 + mt * 16 + (l >> 4) * 4;
      f32x4 v = acc[mt][nt];
      float* p = Out + (size_t)m * DIMQ + n;
      p[0] = v[0]; p[DIMQ] = v[1];
      p[2 * DIMQ] = v[2]; p[3 * DIMQ] = v[3];
    }
  }
}

// ---------------- launcher ----------------
extern "C" void kernel_launch(void* const* d_in, const int* in_sizes, int n_in,
                              void* d_out, int out_size, void* d_ws, size_t ws_size,
                              hipStream_t stream) {
  (void)in_sizes; (void)n_in; (void)out_size; (void)ws_size;
  const float* batch  = (const float*)d_in[0];
  const float* w_qkv  = (const float*)d_in[1];
  const float* w_proj = (const float*)d_in[2];
  const int*   cmask  = (const int*)d_in[3];

  __bf16* Abf = (__bf16*)d_ws;                       // 8192*512 bf16      (8 MB)
  __bf16* WqT = Abf + (size_t)8192 * 512;            // 1536*512           (1.5 MB)
  __bf16* WpT = WqT + (size_t)1536 * 512;            // 512*512            (0.5 MB)
  u64*    mb  = (u64*)(WpT + (size_t)512 * 512);     // 4096*64 u64        (2 MB)
  __bf16* Qh  = (__bf16*)(mb + (size_t)4096 * 64);   // 32*4096*32         (8 MB)
  __bf16* Kh  = Qh + (size_t)32 * NSEQ * HDIM;       //                    (8 MB)
  __bf16* VT  = Kh + (size_t)32 * NSEQ * HDIM;       //                    (8 MB)
  __bf16* Obf = VT + (size_t)32 * NSEQ * HDIM;       // 8192*512 bf16      (8 MB)
  float*  Opart = (float*)(Obf + (size_t)8192 * 512);      // 2 x 16 MB
  float*  Lpart = Opart + (size_t)2 * 8192 * 512;          // 2 x 0.5 MB

  k_cvt_bf16<<<4096, 256, 0, stream>>>(batch, Abf);
  k_cvtT<<<dim3(24, 8), 256, 0, stream>>>(w_qkv, WqT, 1536);
  k_cvtT<<<dim3(8, 8), 256, 0, stream>>>(w_proj, WpT, 512);
  k_maskbits<<<4096, 256, 0, stream>>>(cmask, mb);
  k_gemm_qkv<<<dim3(12, 64), 256, 0, stream>>>(Abf, WqT, Qh, Kh, VT);
  k_attn<<<2048, 256, 0, stream>>>(Qh, Kh, VT, mb, Opart, Lpart);
  k_combine<<<4096, 256, 0, stream>>>(Opart, Lpart, Obf);
  k_gemm_proj<<<dim3(4, 64), 256, 0, stream>>>(Obf, WpT, (float*)d_out);
}

// Round 14
// 243.006 us; speedup vs baseline: 1.0768x; 1.0142x over previous
//
#include <hip/hip_runtime.h>
#include <hip/hip_bf16.h>

typedef __attribute__((ext_vector_type(4))) float f32x4;
typedef __attribute__((ext_vector_type(8))) __bf16 bf16x8;
typedef __attribute__((ext_vector_type(4))) __bf16 bf16x4;
typedef __attribute__((ext_vector_type(4))) unsigned int u32x4;
typedef unsigned long long u64;
typedef unsigned int u32;

#define DIMQ 512
#define NSEQ 4096
#define NHEAD 16
#define HDIM 32
#define SCALE_QK 0.17677669529663687f
#define C2F (SCALE_QK * 1.4426950408889634f)  // scale * log2(e), folded into Q

__device__ __forceinline__ void gload16(void* lds, const void* g) {
  __builtin_amdgcn_global_load_lds(
      (const __attribute__((address_space(1))) void*)g,
      (__attribute__((address_space(3))) void*)lds, 16, 0, 0);
}

// ---------------- conversion kernels ----------------

__global__ __launch_bounds__(256) void k_cvt_bf16(const float* __restrict__ in,
                                                  __bf16* __restrict__ out) {
  int i = blockIdx.x * 256 + threadIdx.x;
  float4 v = reinterpret_cast<const float4*>(in)[i];
  bf16x4 o;
  o.x = (__bf16)v.x; o.y = (__bf16)v.y; o.z = (__bf16)v.z; o.w = (__bf16)v.w;
  reinterpret_cast<bf16x4*>(out)[i] = o;
}

// in: fp32 [512][Nc]  ->  out: bf16 [Nc][512]  (transpose via LDS tile)
__global__ __launch_bounds__(256) void k_cvtT(const float* __restrict__ in,
                                              __bf16* __restrict__ out, int Nc) {
  __shared__ __bf16 t[64][72];
  int k0 = blockIdx.y * 64, n0 = blockIdx.x * 64;
  int c = threadIdx.x & 63, rr = threadIdx.x >> 6;
#pragma unroll
  for (int i = 0; i < 16; ++i) {
    int r = rr * 16 + i;
    t[r][c] = (__bf16)in[(size_t)(k0 + r) * Nc + n0 + c];
  }
  __syncthreads();
#pragma unroll
  for (int i = 0; i < 16; ++i) {
    int r = rr * 16 + i;
    out[(size_t)(n0 + r) * 512 + k0 + c] = t[c][r];
  }
}

// int32 mask [4096][4096] -> PERMUTED bit mask [4096][64] u64.
// Lane l ballots column kvp(l) so the two mask bits of each packed-bf16 pair
// (pa elements 2w,2w+1) sit 16 bits apart:
//   mt bit l  <->  kv = 32*l5 | 16*l1 | (l3:2)*4 | 2*l0 | l4
__global__ __launch_bounds__(256) void k_maskbits(const int* __restrict__ mask,
                                                  u64* __restrict__ bits) {
  int row = blockIdx.x;
  int l = threadIdx.x & 63, w = threadIdx.x >> 6;
  const int jj = l >> 5, odd = (l >> 4) & 1, gg = (l >> 2) & 3, wb = l & 3;
  const int kvp = 32 * jj + 16 * (wb >> 1) + 4 * gg + 2 * (wb & 1) + odd;
  const int* mr = mask + (size_t)row * NSEQ;
  for (int t = w; t < 64; t += 4) {
    u64 b = __ballot(mr[t * 64 + kvp] != 0);
    if (l == 0) bits[(size_t)row * 64 + t] = b;
  }
}

// ---------------- shared GEMM main loop (m97-style, swizzled gload_lds) ----------------
__device__ __forceinline__ void gemm_mainloop(const __bf16* __restrict__ A,
                                              const __bf16* __restrict__ Bt,
                                              int m0, int n0,
                                              __bf16* As, __bf16* Bs,
                                              f32x4 acc[4][4]) {
  const int tid = threadIdx.x, l = tid & 63, w = tid >> 6;
  const int wr = w >> 1, wc = w & 1;
  for (int kt = 0; kt < DIMQ; kt += 64) {
    __syncthreads();
#pragma unroll
    for (int it = 0; it < 4; ++it) {
      int c = it * 256 + tid;
      int row = c >> 3, j = c & 7, js = j ^ (row & 7);
      gload16(As + (size_t)(it * 256 + w * 64) * 8,
              A + (size_t)(m0 + row) * DIMQ + kt + js * 8);
      gload16(Bs + (size_t)(it * 256 + w * 64) * 8,
              Bt + (size_t)(n0 + row) * DIMQ + kt + js * 8);
    }
    __syncthreads();
#pragma unroll
    for (int kk = 0; kk < 2; ++kk) {
      bf16x8 a[4], b[4];
#pragma unroll
      for (int mt = 0; mt < 4; ++mt) {
        int row = wr * 64 + mt * 16 + (l & 15);
        int g = (kk * 4 + (l >> 4)) ^ (row & 7);
        a[mt] = *reinterpret_cast<const bf16x8*>((const char*)As + row * 128 + g * 16);
      }
#pragma unroll
      for (int nt = 0; nt < 4; ++nt) {
        int row = wc * 64 + nt * 16 + (l & 15);
        int g = (kk * 4 + (l >> 4)) ^ (row & 7);
        b[nt] = *reinterpret_cast<const bf16x8*>((const char*)Bs + row * 128 + g * 16);
      }
#pragma unroll
      for (int mt = 0; mt < 4; ++mt)
#pragma unroll
        for (int nt = 0; nt < 4; ++nt)
          acc[mt][nt] = __builtin_amdgcn_mfma_f32_16x16x32_bf16(a[mt], b[nt], acc[mt][nt], 0, 0, 0);
    }
  }
}

// ---------------- QKV GEMM (epilogue: head layout; Q pre-scaled; V transposed + k-permuted) ----------------
__global__ __launch_bounds__(256) void k_gemm_qkv(const __bf16* __restrict__ A,
                                                  const __bf16* __restrict__ Bt,
                                                  __bf16* __restrict__ Qh,
                                                  __bf16* __restrict__ Kh,
                                                  __bf16* __restrict__ VT) {
  __shared__ __bf16 As[128 * 64], Bs[128 * 64];
  f32x4 acc[4][4] = {};
  const int l = threadIdx.x & 63, w = threadIdx.x >> 6, wr = w >> 1, wc = w & 1;
  const int m0 = blockIdx.y * 128, n0 = blockIdx.x * 128;
  gemm_mainloop(A, Bt, m0, n0, As, Bs, acc);
#pragma unroll
  for (int nt = 0; nt < 4; ++nt) {
    int n = n0 + wc * 64 + nt * 16 + (l & 15);
    int sec = n >> 9;           // 0=q 1=k 2=v
    int hh = (n >> 5) & 15;     // head
    int d = n & 31;             // dim in head
#pragma unroll
    for (int mt = 0; mt < 4; ++mt) {
      int m = m0 + wr * 64 + mt * 16 + (l >> 4) * 4;
      int bb = m >> 12, nn = m & 4095;
      size_t bh = (size_t)bb * NHEAD + hh;
      f32x4 v = acc[mt][nt];
      if (sec == 0) {
        __bf16* p = Qh + (bh * NSEQ + nn) * HDIM + d;
        p[0] = (__bf16)(v[0] * C2F); p[HDIM] = (__bf16)(v[1] * C2F);
        p[2 * HDIM] = (__bf16)(v[2] * C2F); p[3 * HDIM] = (__bf16)(v[3] * C2F);
      } else if (sec == 1) {
        __bf16* p = Kh + (bh * NSEQ + nn) * HDIM + d;
        p[0] = (__bf16)v[0]; p[HDIM] = (__bf16)v[1];
        p[2 * HDIM] = (__bf16)v[2]; p[3 * HDIM] = (__bf16)v[3];
      } else {
        // k-permuted V: within each 32-kv group, low5 = hi*16 + g*4 + r -> g*8 + hi*4 + r
        // (nn % 4 == 0, so r = 0 for the vector base)
        int low = nn & 31;
        int nnp = (nn & ~31) | (((low >> 2) & 3) << 3) | (((low >> 4) & 1) << 2);
        bf16x4 o;
        o.x = (__bf16)v[0]; o.y = (__bf16)v[1]; o.z = (__bf16)v[2]; o.w = (__bf16)v[3];
        *reinterpret_cast<bf16x4*>(VT + (bh * HDIM + d) * NSEQ + nnp) = o;
      }
    }
  }
}

// ---------------- fused masked attention, v11: kv-split x2 + KVBLK=128 ----------------
// grid 2048 (sp = bid>>10 kv half; XCD-aware decode), 4 waves x 32 q-rows.
// TWO kv-tiles per barrier phase (independent register chains -> in-wave ILP),
// 32 KB LDS = 2 buf x 2 tiles x (4K K + 4K V). launch_bounds(256,4).
// Per-tile math identical to v7/v10 (packed-AND mask, MFMA row-sums).
__device__ __forceinline__ void attn_compute(const __bf16* __restrict__ Kl,
                                             const __bf16* __restrict__ Vl,
                                             const bf16x8 qf[2], u64 mw0, u64 mw1,
                                             f32x4 acc[2][2], f32x4 accS[2],
                                             int kOff, const int vOff[2][2],
                                             bf16x8 ones, int g) {
  bf16x8 kf[4];
#pragma unroll
  for (int f = 0; f < 4; ++f)
    kf[f] = *reinterpret_cast<const bf16x8*>(Kl + kOff + f * 512);

  bf16x8 vvb[2][2];  // [jj][dt], single b128 each
#pragma unroll
  for (int jj = 0; jj < 2; ++jj)
#pragma unroll
    for (int dt = 0; dt < 2; ++dt)
      vvb[jj][dt] = *reinterpret_cast<const bf16x8*>(Vl + vOff[jj][dt]);

  const f32x4 z4 = {0.f, 0.f, 0.f, 0.f};
#pragma unroll
  for (int rt = 0; rt < 2; ++rt) {
    const u64 mw = rt ? mw1 : mw0;
#pragma unroll
    for (int jj = 0; jj < 2; ++jj) {
      // S^T for kv halves f=2jj, 2jj+1: lane holds q=q16, k=16f+4g+r
      f32x4 s0 = __builtin_amdgcn_mfma_f32_16x16x32_bf16(kf[2 * jj], qf[rt], z4, 0, 0, 0);
      f32x4 s1 = __builtin_amdgcn_mfma_f32_16x16x32_bf16(kf[2 * jj + 1], qf[rt], z4, 0, 0, 0);
      bf16x8 pa;  // k order e = hi*4 + r matches permuted-V b128 order
#pragma unroll
      for (int r = 0; r < 4; ++r) {
        pa[r] = (__bf16)__builtin_exp2f(s0[r]);
        pa[r + 4] = (__bf16)__builtin_exp2f(s1[r]);
      }
      const u32 x = ((u32)(mw >> (32 * jj))) >> (g * 4);
      u32x4 pw = __builtin_bit_cast(u32x4, pa);
#pragma unroll
      for (int wq = 0; wq < 4; ++wq) {
        u32 zb = (x >> wq) & 0x10001u;
        pw[wq] &= (zb << 16) - zb;  // 0 / 0xFFFF / 0xFFFF0000 / 0xFFFFFFFF
      }
      bf16x8 pm = __builtin_bit_cast(bf16x8, pw);
      accS[rt] = __builtin_amdgcn_mfma_f32_16x16x32_bf16(pm, ones, accS[rt], 0, 0, 0);
#pragma unroll
      for (int dt = 0; dt < 2; ++dt)
        acc[rt][dt] =
            __builtin_amdgcn_mfma_f32_16x16x32_bf16(pm, vvb[jj][dt], acc[rt][dt], 0, 0, 0);
    }
  }
}

__global__ __launch_bounds__(256, 4) void k_attn(const __bf16* __restrict__ Qh,
                                                 const __bf16* __restrict__ Kh,
                                                 const __bf16* __restrict__ VT,
                                                 const u64* __restrict__ mbits,
                                                 float* __restrict__ Opart,
                                                 float* __restrict__ Lpart) {
  __shared__ __bf16 Klds[2][2][2048];  // [buf][pair][64 rows x 4 slots], slot-swizzled
  __shared__ __bf16 Vlds[2][2][2048];  // [buf][pair][32 d x 8 granules], granule-swizzled
  const int tid = threadIdx.x;
  const int l = tid & 63, w = tid >> 6;
  const int g = l >> 4, q16 = l & 15;
  const int bid = blockIdx.x;
  const int sp = bid >> 10;                          // kv split: 0 or 1
  const int rest = bid & 1023;
  const int bh = (rest & 7) * 4 + ((rest >> 3) & 3); // XCD-aware decode
  const int qx = rest >> 5;                          // 0..31
  const int q0 = qx * 128 + w * 32;
  const int base = sp * 32;                          // kv tile range [base, base+32)
  const __bf16* Qb = Qh + (size_t)bh * NSEQ * HDIM;
  const __bf16* Kb = Kh + (size_t)bh * NSEQ * HDIM;
  const __bf16* Vb = VT + (size_t)bh * HDIM * NSEQ;  // [32 d][4096 kp]
  const u64* mr0 = mbits + (size_t)(q0 + q16) * 64;
  const u64* mr1 = mbits + (size_t)(q0 + 16 + q16) * 64;

  // staging sources (pre-swizzled: linear LDS dest + swizzled read match)
  const int rk = tid >> 2, gsK = (tid & 3) ^ ((rk >> 1) & 3);
  const __bf16* srcK = Kb + (size_t)rk * HDIM + gsK * 8;   // += t*2048
  const int dv = tid >> 3, gv = (tid & 7) ^ (dv & 7);
  const __bf16* srcV = Vb + (size_t)dv * NSEQ + gv * 8;    // += t*64

  // LDS read offsets (loop-invariant, elements)
  const int kOff = q16 * 32 + (g ^ ((q16 >> 1) & 3)) * 8;
  int vOff[2][2];
#pragma unroll
  for (int jj = 0; jj < 2; ++jj)
#pragma unroll
    for (int dt = 0; dt < 2; ++dt) {
      int d = dt * 16 + q16;
      vOff[jj][dt] = d * 64 + ((4 * jj + g) ^ (d & 7)) * 8;
    }

  bf16x8 qf[2];
#pragma unroll
  for (int rt = 0; rt < 2; ++rt)
    qf[rt] = *reinterpret_cast<const bf16x8*>(
        Qb + (size_t)(q0 + rt * 16 + q16) * HDIM + g * 8);

  bf16x8 ones;
#pragma unroll
  for (int e = 0; e < 8; ++e) ones[e] = (__bf16)1.0f;

  f32x4 acc[2][2] = {};
  f32x4 accS[2] = {};

  // prologue: stage tiles base, base+1 into buf0 (pairs 0,1)
  gload16(&Klds[0][0][0] + tid * 8, srcK + (size_t)base * 2048);
  gload16(&Vlds[0][0][0] + tid * 8, srcV + (size_t)base * 64);
  gload16(&Klds[0][1][0] + tid * 8, srcK + (size_t)(base + 1) * 2048);
  gload16(&Vlds[0][1][0] + tid * 8, srcV + (size_t)(base + 1) * 64);
  u64 a0 = mr0[base], a1 = mr1[base];
  u64 a2 = mr0[base + 1], a3 = mr1[base + 1];
  u64 b0, b1, b2, b3;
  __syncthreads();

  for (int t = base; t < base + 32; t += 4) {
    // phase A: stage t+2,t+3 -> buf1; compute t,t+1 from buf0 (2 indep chains)
    gload16(&Klds[1][0][0] + tid * 8, srcK + (size_t)(t + 2) * 2048);
    gload16(&Vlds[1][0][0] + tid * 8, srcV + (size_t)(t + 2) * 64);
    gload16(&Klds[1][1][0] + tid * 8, srcK + (size_t)(t + 3) * 2048);
    gload16(&Vlds[1][1][0] + tid * 8, srcV + (size_t)(t + 3) * 64);
    b0 = mr0[t + 2]; b1 = mr1[t + 2]; b2 = mr0[t + 3]; b3 = mr1[t + 3];
    attn_compute(&Klds[0][0][0], &Vlds[0][0][0], qf, a0, a1, acc, accS, kOff, vOff, ones, g);
    attn_compute(&Klds[0][1][0], &Vlds[0][1][0], qf, a2, a3, acc, accS, kOff, vOff, ones, g);
    __syncthreads();
    // phase B: stage t+4,t+5 (clamped) -> buf0; compute t+2,t+3 from buf1
    const int t4 = (t + 4 < base + 32) ? t + 4 : base + 30;
    gload16(&Klds[0][0][0] + tid * 8, srcK + (size_t)t4 * 2048);
    gload16(&Vlds[0][0][0] + tid * 8, srcV + (size_t)t4 * 64);
    gload16(&Klds[0][1][0] + tid * 8, srcK + (size_t)(t4 + 1) * 2048);
    gload16(&Vlds[0][1][0] + tid * 8, srcV + (size_t)(t4 + 1) * 64);
    a0 = mr0[t4]; a1 = mr1[t4]; a2 = mr0[t4 + 1]; a3 = mr1[t4 + 1];
    attn_compute(&Klds[1][0][0], &Vlds[1][0][0], qf, b0, b1, acc, accS, kOff, vOff, ones, g);
    attn_compute(&Klds[1][1][0], &Vlds[1][1][0], qf, b2, b3, acc, accS, kOff, vOff, ones, g);
    __syncthreads();
  }

  const int bb = bh >> 4, hh = bh & 15;
  float* Op = Opart + (size_t)sp * 8192 * 512;
  float* Lp = Lpart + (size_t)sp * 32 * 4096;
#pragma unroll
  for (int rt = 0; rt < 2; ++rt)
#pragma unroll
    for (int r = 0; r < 4; ++r) {
      int qrow = q0 + rt * 16 + g * 4 + r;
      if (q16 == 0) Lp[(size_t)bh * 4096 + qrow] = accS[rt][r];
#pragma unroll
      for (int dt = 0; dt < 2; ++dt)
        Op[((size_t)bb * NSEQ + qrow) * DIMQ + hh * HDIM + dt * 16 + q16] =
            acc[rt][dt][r];
    }
}

// ---------------- split combine: Obf = (Op0+Op1) / (L0+L1) ----------------
__global__ __launch_bounds__(256) void k_combine(const float* __restrict__ Opart,
                                                 const float* __restrict__ Lpart,
                                                 __bf16* __restrict__ Obf) {
  const int i = blockIdx.x * 256 + threadIdx.x;  // handles 4 consecutive elems
  const size_t base = (size_t)i * 4;
  const int m = (int)(base >> 9), n = (int)(base & 511);
  const int bb = m >> 12, nn = m & 4095, hh = n >> 5;
  float4 a = *reinterpret_cast<const float4*>(Opart + base);
  float4 b = *reinterpret_cast<const float4*>(Opart + (size_t)8192 * 512 + base);
  const size_t li = ((size_t)(bb * 16 + hh)) * 4096 + nn;
  float inv = 1.f / (Lpart[li] + Lpart[(size_t)32 * 4096 + li]);
  bf16x4 o;
  o.x = (__bf16)((a.x + b.x) * inv);
  o.y = (__bf16)((a.y + b.y) * inv);
  o.z = (__bf16)((a.z + b.z) * inv);
  o.w = (__bf16)((a.w + b.w) * inv);
  *reinterpret_cast<bf16x4*>(Obf + base) = o;
}

// ---------------- output projection GEMM (fp32 output) ----------------
__global__ __launch_bounds__(256) void k_gemm_proj(const __bf16* __restrict__ A,
                                                   const __bf16* __restrict__ Bt,
                                                   float* __restrict__ Out) {
  __shared__ __bf16 As[128 * 64], Bs[128 * 64];
  f32x4 acc[4][4] = {};
  const int l = threadIdx.x & 63, w = threadIdx.x >> 6, wr = w >> 1, wc = w & 1;
  const int m0 = blockIdx.y * 128, n0 = blockIdx.x * 128;
  gemm_mainloop(A, Bt, m0, n0, As, Bs, acc);
#pragma unroll
  for (int nt = 0; nt < 4; ++nt) {
    int n = n0 + wc * 64 + nt * 16 + (l & 15);
#pragma unroll
    for (int mt = 0; mt < 4; ++mt) {
      int m = m0 + wr * 64 + mt * 16 + (l >> 4) * 4;
      f32x4 v = acc[mt][nt];
      float* p = Out + (size_t)m * DIMQ + n;
      p[0] = v[0]; p[DIMQ] = v[1];
      p[2 * DIMQ] = v[2]; p[3 * DIMQ] = v[3];
    }
  }
}

// ---------------- launcher ----------------
extern "C" void kernel_launch(void* const* d_in, const int* in_sizes, int n_in,
                              void* d_out, int out_size, void* d_ws, size_t ws_size,
                              hipStream_t stream) {
  (void)in_sizes; (void)n_in; (void)out_size; (void)ws_size;
  const float* batch  = (const float*)d_in[0];
  const float* w_qkv  = (const float*)d_in[1];
  const float* w_proj = (const float*)d_in[2];
  const int*   cmask  = (const int*)d_in[3];

  __bf16* Abf = (__bf16*)d_ws;                       // 8192*512 bf16      (8 MB)
  __bf16* WqT = Abf + (size_t)8192 * 512;            // 1536*512           (1.5 MB)
  __bf16* WpT = WqT + (size_t)1536 * 512;            // 512*512            (0.5 MB)
  u64*    mb  = (u64*)(WpT + (size_t)512 * 512);     // 4096*64 u64        (2 MB)
  __bf16* Qh  = (__bf16*)(mb + (size_t)4096 * 64);   // 32*4096*32         (8 MB)
  __bf16* Kh  = Qh + (size_t)32 * NSEQ * HDIM;       //                    (8 MB)
  __bf16* VT  = Kh + (size_t)32 * NSEQ * HDIM;       //                    (8 MB)
  __bf16* Obf = VT + (size_t)32 * NSEQ * HDIM;       // 8192*512 bf16      (8 MB)
  float*  Opart = (float*)(Obf + (size_t)8192 * 512);      // 2 x 16 MB
  float*  Lpart = Opart + (size_t)2 * 8192 * 512;          // 2 x 0.5 MB

  k_cvt_bf16<<<4096, 256, 0, stream>>>(batch, Abf);
  k_cvtT<<<dim3(24, 8), 256, 0, stream>>>(w_qkv, WqT, 1536);
  k_cvtT<<<dim3(8, 8), 256, 0, stream>>>(w_proj, WpT, 512);
  k_maskbits<<<4096, 256, 0, stream>>>(cmask, mb);
  k_gemm_qkv<<<dim3(12, 64), 256, 0, stream>>>(Abf, WqT, Qh, Kh, VT);
  k_attn<<<2048, 256, 0, stream>>>(Qh, Kh, VT, mb, Opart, Lpart);
  k_combine<<<4096, 256, 0, stream>>>(Opart, Lpart, Obf);
  k_gemm_proj<<<dim3(4, 64), 256, 0, stream>>>(Obf, WpT, (float*)d_out);
}

// Round 15
// 206.978 us; speedup vs baseline: 1.2643x; 1.1741x over previous
//
#include <hip/hip_runtime.h>
#include <hip/hip_bf16.h>

typedef __attribute__((ext_vector_type(4))) float f32x4;
typedef __attribute__((ext_vector_type(8))) __bf16 bf16x8;
typedef __attribute__((ext_vector_type(4))) __bf16 bf16x4;
typedef __attribute__((ext_vector_type(4))) unsigned int u32x4;
typedef unsigned long long u64;
typedef unsigned int u32;

#define DIMQ 512
#define NSEQ 4096
#define NHEAD 16
#define HDIM 32
#define SCALE_QK 0.17677669529663687f
#define C2F (SCALE_QK * 1.4426950408889634f)  // scale * log2(e), folded into Q

__device__ __forceinline__ void gload16(void* lds, const void* g) {
  __builtin_amdgcn_global_load_lds(
      (const __attribute__((address_space(1))) void*)g,
      (__attribute__((address_space(3))) void*)lds, 16, 0, 0);
}

// raw v_exp_f32: args are statically bounded (|x| <= ~52), masked lanes are
// AND-zeroed afterward, so no ocml denormal/range fixup is needed.
__device__ __forceinline__ float fast_exp2(float x) {
#if __has_builtin(__builtin_amdgcn_exp2f)
  return __builtin_amdgcn_exp2f(x);
#else
  float r;
  asm("v_exp_f32 %0, %1" : "=v"(r) : "v"(x));
  return r;
#endif
}

// ---------------- conversion kernels ----------------

__global__ __launch_bounds__(256) void k_cvt_bf16(const float* __restrict__ in,
                                                  __bf16* __restrict__ out) {
  int i = blockIdx.x * 256 + threadIdx.x;
  float4 v = reinterpret_cast<const float4*>(in)[i];
  bf16x4 o;
  o.x = (__bf16)v.x; o.y = (__bf16)v.y; o.z = (__bf16)v.z; o.w = (__bf16)v.w;
  reinterpret_cast<bf16x4*>(out)[i] = o;
}

// in: fp32 [512][Nc]  ->  out: bf16 [Nc][512]  (transpose via LDS tile)
__global__ __launch_bounds__(256) void k_cvtT(const float* __restrict__ in,
                                              __bf16* __restrict__ out, int Nc) {
  __shared__ __bf16 t[64][72];
  int k0 = blockIdx.y * 64, n0 = blockIdx.x * 64;
  int c = threadIdx.x & 63, rr = threadIdx.x >> 6;
#pragma unroll
  for (int i = 0; i < 16; ++i) {
    int r = rr * 16 + i;
    t[r][c] = (__bf16)in[(size_t)(k0 + r) * Nc + n0 + c];
  }
  __syncthreads();
#pragma unroll
  for (int i = 0; i < 16; ++i) {
    int r = rr * 16 + i;
    out[(size_t)(n0 + r) * 512 + k0 + c] = t[c][r];
  }
}

// int32 mask [4096][4096] -> PERMUTED bit mask [4096][64] u64.
// Lane l ballots column kvp(l) so the two mask bits of each packed-bf16 pair
// (pa elements 2w,2w+1) sit 16 bits apart:
//   mt bit l  <->  kv = 32*l5 | 16*l1 | (l3:2)*4 | 2*l0 | l4
__global__ __launch_bounds__(256) void k_maskbits(const int* __restrict__ mask,
                                                  u64* __restrict__ bits) {
  int row = blockIdx.x;
  int l = threadIdx.x & 63, w = threadIdx.x >> 6;
  const int jj = l >> 5, odd = (l >> 4) & 1, gg = (l >> 2) & 3, wb = l & 3;
  const int kvp = 32 * jj + 16 * (wb >> 1) + 4 * gg + 2 * (wb & 1) + odd;
  const int* mr = mask + (size_t)row * NSEQ;
  for (int t = w; t < 64; t += 4) {
    u64 b = __ballot(mr[t * 64 + kvp] != 0);
    if (l == 0) bits[(size_t)row * 64 + t] = b;
  }
}

// ---------------- shared GEMM main loop (m97-style, swizzled gload_lds) ----------------
__device__ __forceinline__ void gemm_mainloop(const __bf16* __restrict__ A,
                                              const __bf16* __restrict__ Bt,
                                              int m0, int n0,
                                              __bf16* As, __bf16* Bs,
                                              f32x4 acc[4][4]) {
  const int tid = threadIdx.x, l = tid & 63, w = tid >> 6;
  const int wr = w >> 1, wc = w & 1;
  for (int kt = 0; kt < DIMQ; kt += 64) {
    __syncthreads();
#pragma unroll
    for (int it = 0; it < 4; ++it) {
      int c = it * 256 + tid;
      int row = c >> 3, j = c & 7, js = j ^ (row & 7);
      gload16(As + (size_t)(it * 256 + w * 64) * 8,
              A + (size_t)(m0 + row) * DIMQ + kt + js * 8);
      gload16(Bs + (size_t)(it * 256 + w * 64) * 8,
              Bt + (size_t)(n0 + row) * DIMQ + kt + js * 8);
    }
    __syncthreads();
#pragma unroll
    for (int kk = 0; kk < 2; ++kk) {
      bf16x8 a[4], b[4];
#pragma unroll
      for (int mt = 0; mt < 4; ++mt) {
        int row = wr * 64 + mt * 16 + (l & 15);
        int g = (kk * 4 + (l >> 4)) ^ (row & 7);
        a[mt] = *reinterpret_cast<const bf16x8*>((const char*)As + row * 128 + g * 16);
      }
#pragma unroll
      for (int nt = 0; nt < 4; ++nt) {
        int row = wc * 64 + nt * 16 + (l & 15);
        int g = (kk * 4 + (l >> 4)) ^ (row & 7);
        b[nt] = *reinterpret_cast<const bf16x8*>((const char*)Bs + row * 128 + g * 16);
      }
#pragma unroll
      for (int mt = 0; mt < 4; ++mt)
#pragma unroll
        for (int nt = 0; nt < 4; ++nt)
          acc[mt][nt] = __builtin_amdgcn_mfma_f32_16x16x32_bf16(a[mt], b[nt], acc[mt][nt], 0, 0, 0);
    }
  }
}

// ---------------- QKV GEMM (epilogue: head layout; Q pre-scaled; V transposed + k-permuted) ----------------
__global__ __launch_bounds__(256) void k_gemm_qkv(const __bf16* __restrict__ A,
                                                  const __bf16* __restrict__ Bt,
                                                  __bf16* __restrict__ Qh,
                                                  __bf16* __restrict__ Kh,
                                                  __bf16* __restrict__ VT) {
  __shared__ __bf16 As[128 * 64], Bs[128 * 64];
  f32x4 acc[4][4] = {};
  const int l = threadIdx.x & 63, w = threadIdx.x >> 6, wr = w >> 1, wc = w & 1;
  const int m0 = blockIdx.y * 128, n0 = blockIdx.x * 128;
  gemm_mainloop(A, Bt, m0, n0, As, Bs, acc);
#pragma unroll
  for (int nt = 0; nt < 4; ++nt) {
    int n = n0 + wc * 64 + nt * 16 + (l & 15);
    int sec = n >> 9;           // 0=q 1=k 2=v
    int hh = (n >> 5) & 15;     // head
    int d = n & 31;             // dim in head
#pragma unroll
    for (int mt = 0; mt < 4; ++mt) {
      int m = m0 + wr * 64 + mt * 16 + (l >> 4) * 4;
      int bb = m >> 12, nn = m & 4095;
      size_t bh = (size_t)bb * NHEAD + hh;
      f32x4 v = acc[mt][nt];
      if (sec == 0) {
        __bf16* p = Qh + (bh * NSEQ + nn) * HDIM + d;
        p[0] = (__bf16)(v[0] * C2F); p[HDIM] = (__bf16)(v[1] * C2F);
        p[2 * HDIM] = (__bf16)(v[2] * C2F); p[3 * HDIM] = (__bf16)(v[3] * C2F);
      } else if (sec == 1) {
        __bf16* p = Kh + (bh * NSEQ + nn) * HDIM + d;
        p[0] = (__bf16)v[0]; p[HDIM] = (__bf16)v[1];
        p[2 * HDIM] = (__bf16)v[2]; p[3 * HDIM] = (__bf16)v[3];
      } else {
        // k-permuted V: within each 32-kv group, low5 = hi*16 + g*4 + r -> g*8 + hi*4 + r
        // (nn % 4 == 0, so r = 0 for the vector base)
        int low = nn & 31;
        int nnp = (nn & ~31) | (((low >> 2) & 3) << 3) | (((low >> 4) & 1) << 2);
        bf16x4 o;
        o.x = (__bf16)v[0]; o.y = (__bf16)v[1]; o.z = (__bf16)v[2]; o.w = (__bf16)v[3];
        *reinterpret_cast<bf16x4*>(VT + (bh * HDIM + d) * NSEQ + nnp) = o;
      }
    }
  }
}

// ---------------- fused masked attention, v12: v11 + raw v_exp + wide mask loads ----------------
__device__ __forceinline__ void attn_compute(const __bf16* __restrict__ Kl,
                                             const __bf16* __restrict__ Vl,
                                             const bf16x8 qf[2], u64 mw0, u64 mw1,
                                             f32x4 acc[2][2], f32x4 accS[2],
                                             int kOff, const int vOff[2][2],
                                             bf16x8 ones, int g) {
  bf16x8 kf[4];
#pragma unroll
  for (int f = 0; f < 4; ++f)
    kf[f] = *reinterpret_cast<const bf16x8*>(Kl + kOff + f * 512);

  bf16x8 vvb[2][2];  // [jj][dt], single b128 each
#pragma unroll
  for (int jj = 0; jj < 2; ++jj)
#pragma unroll
    for (int dt = 0; dt < 2; ++dt)
      vvb[jj][dt] = *reinterpret_cast<const bf16x8*>(Vl + vOff[jj][dt]);

  const f32x4 z4 = {0.f, 0.f, 0.f, 0.f};
#pragma unroll
  for (int rt = 0; rt < 2; ++rt) {
    const u64 mw = rt ? mw1 : mw0;
#pragma unroll
    for (int jj = 0; jj < 2; ++jj) {
      // S^T for kv halves f=2jj, 2jj+1: lane holds q=q16, k=16f+4g+r
      f32x4 s0 = __builtin_amdgcn_mfma_f32_16x16x32_bf16(kf[2 * jj], qf[rt], z4, 0, 0, 0);
      f32x4 s1 = __builtin_amdgcn_mfma_f32_16x16x32_bf16(kf[2 * jj + 1], qf[rt], z4, 0, 0, 0);
      bf16x8 pa;  // k order e = hi*4 + r matches permuted-V b128 order
#pragma unroll
      for (int r = 0; r < 4; ++r) {
        pa[r] = (__bf16)fast_exp2(s0[r]);
        pa[r + 4] = (__bf16)fast_exp2(s1[r]);
      }
      const u32 x = ((u32)(mw >> (32 * jj))) >> (g * 4);
      u32x4 pw = __builtin_bit_cast(u32x4, pa);
#pragma unroll
      for (int wq = 0; wq < 4; ++wq) {
        u32 zb = (x >> wq) & 0x10001u;
        pw[wq] &= (zb << 16) - zb;  // 0 / 0xFFFF / 0xFFFF0000 / 0xFFFFFFFF
      }
      bf16x8 pm = __builtin_bit_cast(bf16x8, pw);
      accS[rt] = __builtin_amdgcn_mfma_f32_16x16x32_bf16(pm, ones, accS[rt], 0, 0, 0);
#pragma unroll
      for (int dt = 0; dt < 2; ++dt)
        acc[rt][dt] =
            __builtin_amdgcn_mfma_f32_16x16x32_bf16(pm, vvb[jj][dt], acc[rt][dt], 0, 0, 0);
    }
  }
}

__global__ __launch_bounds__(256, 4) void k_attn(const __bf16* __restrict__ Qh,
                                                 const __bf16* __restrict__ Kh,
                                                 const __bf16* __restrict__ VT,
                                                 const u64* __restrict__ mbits,
                                                 float* __restrict__ Opart,
                                                 float* __restrict__ Lpart) {
  __shared__ __bf16 Klds[2][2][2048];  // [buf][pair][64 rows x 4 slots], slot-swizzled
  __shared__ __bf16 Vlds[2][2][2048];  // [buf][pair][32 d x 8 granules], granule-swizzled
  const int tid = threadIdx.x;
  const int l = tid & 63, w = tid >> 6;
  const int g = l >> 4, q16 = l & 15;
  const int bid = blockIdx.x;
  const int sp = bid >> 10;                          // kv split: 0 or 1
  const int rest = bid & 1023;
  const int bh = (rest & 7) * 4 + ((rest >> 3) & 3); // XCD-aware decode
  const int qx = rest >> 5;                          // 0..31
  const int q0 = qx * 128 + w * 32;
  const int base = sp * 32;                          // kv tile range [base, base+32)
  const __bf16* Qb = Qh + (size_t)bh * NSEQ * HDIM;
  const __bf16* Kb = Kh + (size_t)bh * NSEQ * HDIM;
  const __bf16* Vb = VT + (size_t)bh * HDIM * NSEQ;  // [32 d][4096 kp]
  const u64* mr0 = mbits + (size_t)(q0 + q16) * 64;
  const u64* mr1 = mbits + (size_t)(q0 + 16 + q16) * 64;

  // staging sources (pre-swizzled: linear LDS dest + swizzled read match)
  const int rk = tid >> 2, gsK = (tid & 3) ^ ((rk >> 1) & 3);
  const __bf16* srcK = Kb + (size_t)rk * HDIM + gsK * 8;   // += t*2048
  const int dv = tid >> 3, gv = (tid & 7) ^ (dv & 7);
  const __bf16* srcV = Vb + (size_t)dv * NSEQ + gv * 8;    // += t*64

  // LDS read offsets (loop-invariant, elements)
  const int kOff = q16 * 32 + (g ^ ((q16 >> 1) & 3)) * 8;
  int vOff[2][2];
#pragma unroll
  for (int jj = 0; jj < 2; ++jj)
#pragma unroll
    for (int dt = 0; dt < 2; ++dt) {
      int d = dt * 16 + q16;
      vOff[jj][dt] = d * 64 + ((4 * jj + g) ^ (d & 7)) * 8;
    }

  bf16x8 qf[2];
#pragma unroll
  for (int rt = 0; rt < 2; ++rt)
    qf[rt] = *reinterpret_cast<const bf16x8*>(
        Qb + (size_t)(q0 + rt * 16 + q16) * HDIM + g * 8);

  bf16x8 ones;
#pragma unroll
  for (int e = 0; e < 8; ++e) ones[e] = (__bf16)1.0f;

  f32x4 acc[2][2] = {};
  f32x4 accS[2] = {};

  // prologue: stage tiles base, base+1 into buf0 (pairs 0,1); wide mask loads
  gload16(&Klds[0][0][0] + tid * 8, srcK + (size_t)base * 2048);
  gload16(&Vlds[0][0][0] + tid * 8, srcV + (size_t)base * 64);
  gload16(&Klds[0][1][0] + tid * 8, srcK + (size_t)(base + 1) * 2048);
  gload16(&Vlds[0][1][0] + tid * 8, srcV + (size_t)(base + 1) * 64);
  u64 a0, a1, a2, a3, b0, b1, b2, b3;
  {
    ulonglong2 m0v = *reinterpret_cast<const ulonglong2*>(mr0 + base);
    ulonglong2 m1v = *reinterpret_cast<const ulonglong2*>(mr1 + base);
    a0 = m0v.x; a2 = m0v.y; a1 = m1v.x; a3 = m1v.y;
  }
  __syncthreads();

  for (int t = base; t < base + 32; t += 4) {
    // phase A: stage t+2,t+3 -> buf1; compute t,t+1 from buf0
    gload16(&Klds[1][0][0] + tid * 8, srcK + (size_t)(t + 2) * 2048);
    gload16(&Vlds[1][0][0] + tid * 8, srcV + (size_t)(t + 2) * 64);
    gload16(&Klds[1][1][0] + tid * 8, srcK + (size_t)(t + 3) * 2048);
    gload16(&Vlds[1][1][0] + tid * 8, srcV + (size_t)(t + 3) * 64);
    {
      ulonglong2 m0v = *reinterpret_cast<const ulonglong2*>(mr0 + t + 2);
      ulonglong2 m1v = *reinterpret_cast<const ulonglong2*>(mr1 + t + 2);
      b0 = m0v.x; b2 = m0v.y; b1 = m1v.x; b3 = m1v.y;
    }
    attn_compute(&Klds[0][0][0], &Vlds[0][0][0], qf, a0, a1, acc, accS, kOff, vOff, ones, g);
    attn_compute(&Klds[0][1][0], &Vlds[0][1][0], qf, a2, a3, acc, accS, kOff, vOff, ones, g);
    __syncthreads();
    // phase B: stage t+4,t+5 (clamped) -> buf0; compute t+2,t+3 from buf1
    const int t4 = (t + 4 < base + 32) ? t + 4 : base + 30;
    gload16(&Klds[0][0][0] + tid * 8, srcK + (size_t)t4 * 2048);
    gload16(&Vlds[0][0][0] + tid * 8, srcV + (size_t)t4 * 64);
    gload16(&Klds[0][1][0] + tid * 8, srcK + (size_t)(t4 + 1) * 2048);
    gload16(&Vlds[0][1][0] + tid * 8, srcV + (size_t)(t4 + 1) * 64);
    {
      ulonglong2 m0v = *reinterpret_cast<const ulonglong2*>(mr0 + t4);
      ulonglong2 m1v = *reinterpret_cast<const ulonglong2*>(mr1 + t4);
      a0 = m0v.x; a2 = m0v.y; a1 = m1v.x; a3 = m1v.y;
    }
    attn_compute(&Klds[1][0][0], &Vlds[1][0][0], qf, b0, b1, acc, accS, kOff, vOff, ones, g);
    attn_compute(&Klds[1][1][0], &Vlds[1][1][0], qf, b2, b3, acc, accS, kOff, vOff, ones, g);
    __syncthreads();
  }

  const int bb = bh >> 4, hh = bh & 15;
  float* Op = Opart + (size_t)sp * 8192 * 512;
  float* Lp = Lpart + (size_t)sp * 32 * 4096;
#pragma unroll
  for (int rt = 0; rt < 2; ++rt)
#pragma unroll
    for (int r = 0; r < 4; ++r) {
      int qrow = q0 + rt * 16 + g * 4 + r;
      if (q16 == 0) Lp[(size_t)bh * 4096 + qrow] = accS[rt][r];
#pragma unroll
      for (int dt = 0; dt < 2; ++dt)
        Op[((size_t)bb * NSEQ + qrow) * DIMQ + hh * HDIM + dt * 16 + q16] =
            acc[rt][dt][r];
    }
}

// ---------------- output projection GEMM, fused with split-combine ----------------
// A[m][k] = (Op0[m][k] + Op1[m][k]) / (L0+L1)[row m, head k>>5], built in-register
// and ds_written to the SAME swizzled LDS slot gload16 used. B via gload16.
__global__ __launch_bounds__(256) void k_gemm_proj(const float* __restrict__ Op,
                                                   const float* __restrict__ Lp,
                                                   const __bf16* __restrict__ Bt,
                                                   float* __restrict__ Out) {
  __shared__ __bf16 As[128 * 64], Bs[128 * 64];
  f32x4 acc[4][4] = {};
  const int tid = threadIdx.x;
  const int l = tid & 63, w = tid >> 6, wr = w >> 1, wc = w & 1;
  const int m0 = blockIdx.y * 128, n0 = blockIdx.x * 128;
  for (int kt = 0; kt < DIMQ; kt += 64) {
    __syncthreads();
#pragma unroll
    for (int it = 0; it < 4; ++it) {
      int c = it * 256 + tid;
      int row = c >> 3, j = c & 7, js = j ^ (row & 7);
      int m = m0 + row, col = kt + js * 8;
      const float* p0 = Op + (size_t)m * DIMQ + col;
      const float* p1 = p0 + (size_t)8192 * 512;
      float4 x0 = *reinterpret_cast<const float4*>(p0);
      float4 x1 = *reinterpret_cast<const float4*>(p0 + 4);
      float4 y0 = *reinterpret_cast<const float4*>(p1);
      float4 y1 = *reinterpret_cast<const float4*>(p1 + 4);
      const int bb = m >> 12, nn = m & 4095, hh = col >> 5;
      const size_t li = ((size_t)(bb * 16 + hh)) * 4096 + nn;
      float inv = 1.f / (Lp[li] + Lp[(size_t)32 * 4096 + li]);
      bf16x8 av;
      av[0] = (__bf16)((x0.x + y0.x) * inv);
      av[1] = (__bf16)((x0.y + y0.y) * inv);
      av[2] = (__bf16)((x0.z + y0.z) * inv);
      av[3] = (__bf16)((x0.w + y0.w) * inv);
      av[4] = (__bf16)((x1.x + y1.x) * inv);
      av[5] = (__bf16)((x1.y + y1.y) * inv);
      av[6] = (__bf16)((x1.z + y1.z) * inv);
      av[7] = (__bf16)((x1.w + y1.w) * inv);
      *reinterpret_cast<bf16x8*>(As + (size_t)c * 8) = av;
      gload16(Bs + (size_t)(it * 256 + w * 64) * 8,
              Bt + (size_t)(n0 + row) * DIMQ + kt + js * 8);
    }
    __syncthreads();
#pragma unroll
    for (int kk = 0; kk < 2; ++kk) {
      bf16x8 a[4], b[4];
#pragma unroll
      for (int mt = 0; mt < 4; ++mt) {
        int row = wr * 64 + mt * 16 + (l & 15);
        int g = (kk * 4 + (l >> 4)) ^ (row & 7);
        a[mt] = *reinterpret_cast<const bf16x8*>((const char*)As + row * 128 + g * 16);
      }
#pragma unroll
      for (int nt = 0; nt < 4; ++nt) {
        int row = wc * 64 + nt * 16 + (l & 15);
        int g = (kk * 4 + (l >> 4)) ^ (row & 7);
        b[nt] = *reinterpret_cast<const bf16x8*>((const char*)Bs + row * 128 + g * 16);
      }
#pragma unroll
      for (int mt = 0; mt < 4; ++mt)
#pragma unroll
        for (int nt = 0; nt < 4; ++nt)
          acc[mt][nt] = __builtin_amdgcn_mfma_f32_16x16x32_bf16(a[mt], b[nt], acc[mt][nt], 0, 0, 0);
    }
  }
#pragma unroll
  for (int nt = 0; nt < 4; ++nt) {
    int n = n0 + wc * 64 + nt * 16 + (l & 15);
#pragma unroll
    for (int mt = 0; mt < 4; ++mt) {
      int m = m0 + wr * 64 + mt * 16 + (l >> 4) * 4;
      f32x4 v = acc[mt][nt];
      float* p = Out + (size_t)m * DIMQ + n;
      p[0] = v[0]; p[DIMQ] = v[1];
      p[2 * DIMQ] = v[2]; p[3 * DIMQ] = v[3];
    }
  }
}

// ---------------- launcher ----------------
extern "C" void kernel_launch(void* const* d_in, const int* in_sizes, int n_in,
                              void* d_out, int out_size, void* d_ws, size_t ws_size,
                              hipStream_t stream) {
  (void)in_sizes; (void)n_in; (void)out_size; (void)ws_size;
  const float* batch  = (const float*)d_in[0];
  const float* w_qkv  = (const float*)d_in[1];
  const float* w_proj = (const float*)d_in[2];
  const int*   cmask  = (const int*)d_in[3];

  __bf16* Abf = (__bf16*)d_ws;                       // 8192*512 bf16      (8 MB)
  __bf16* WqT = Abf + (size_t)8192 * 512;            // 1536*512           (1.5 MB)
  __bf16* WpT = WqT + (size_t)1536 * 512;            // 512*512            (0.5 MB)
  u64*    mb  = (u64*)(WpT + (size_t)512 * 512);     // 4096*64 u64        (2 MB)
  __bf16* Qh  = (__bf16*)(mb + (size_t)4096 * 64);   // 32*4096*32         (8 MB)
  __bf16* Kh  = Qh + (size_t)32 * NSEQ * HDIM;       //                    (8 MB)
  __bf16* VT  = Kh + (size_t)32 * NSEQ * HDIM;       //                    (8 MB)
  float*  Opart = (float*)(VT + (size_t)32 * NSEQ * HDIM); // 2 x 16 MB
  float*  Lpart = Opart + (size_t)2 * 8192 * 512;          // 2 x 0.5 MB

  k_cvt_bf16<<<4096, 256, 0, stream>>>(batch, Abf);
  k_cvtT<<<dim3(24, 8), 256, 0, stream>>>(w_qkv, WqT, 1536);
  k_cvtT<<<dim3(8, 8), 256, 0, stream>>>(w_proj, WpT, 512);
  k_maskbits<<<4096, 256, 0, stream>>>(cmask, mb);
  k_gemm_qkv<<<dim3(12, 64), 256, 0, stream>>>(Abf, WqT, Qh, Kh, VT);
  k_attn<<<2048, 256, 0, stream>>>(Qh, Kh, VT, mb, Opart, Lpart);
  k_gemm_proj<<<dim3(4, 64), 256, 0, stream>>>(Opart, Lpart, WpT, (float*)d_out);
}

// Round 17
// 200.135 us; speedup vs baseline: 1.3075x; 1.0342x over previous
//
#include <hip/hip_runtime.h>
#include <hip/hip_bf16.h>

typedef __attribute__((ext_vector_type(4))) float f32x4;
typedef __attribute__((ext_vector_type(8))) __bf16 bf16x8;
typedef __attribute__((ext_vector_type(4))) __bf16 bf16x4;
typedef __attribute__((ext_vector_type(4))) unsigned int u32x4;
typedef unsigned long long u64;
typedef unsigned int u32;

#define DIMQ 512
#define NSEQ 4096
#define NHEAD 16
#define HDIM 32
#define SCALE_QK 0.17677669529663687f
#define C2F (SCALE_QK * 1.4426950408889634f)  // scale * log2(e), folded into Q

__device__ __forceinline__ void gload16(void* lds, const void* g) {
  __builtin_amdgcn_global_load_lds(
      (const __attribute__((address_space(1))) void*)g,
      (__attribute__((address_space(3))) void*)lds, 16, 0, 0);
}

// raw v_exp_f32: args are statically bounded (|x| <= ~52), masked lanes are
// AND-zeroed afterward, so no ocml denormal/range fixup is needed.
__device__ __forceinline__ float fast_exp2(float x) {
#if __has_builtin(__builtin_amdgcn_exp2f)
  return __builtin_amdgcn_exp2f(x);
#else
  float r;
  asm("v_exp_f32 %0, %1" : "=v"(r) : "v"(x));
  return r;
#endif
}

// ---------------- conversion kernels ----------------

__global__ __launch_bounds__(256) void k_cvt_bf16(const float* __restrict__ in,
                                                  __bf16* __restrict__ out) {
  int i = blockIdx.x * 256 + threadIdx.x;
  float4 v = reinterpret_cast<const float4*>(in)[i];
  bf16x4 o;
  o.x = (__bf16)v.x; o.y = (__bf16)v.y; o.z = (__bf16)v.z; o.w = (__bf16)v.w;
  reinterpret_cast<bf16x4*>(out)[i] = o;
}

// in: fp32 [512][Nc]  ->  out: bf16 [Nc][512]  (transpose via LDS tile)
__global__ __launch_bounds__(256) void k_cvtT(const float* __restrict__ in,
                                              __bf16* __restrict__ out, int Nc) {
  __shared__ __bf16 t[64][72];
  int k0 = blockIdx.y * 64, n0 = blockIdx.x * 64;
  int c = threadIdx.x & 63, rr = threadIdx.x >> 6;
#pragma unroll
  for (int i = 0; i < 16; ++i) {
    int r = rr * 16 + i;
    t[r][c] = (__bf16)in[(size_t)(k0 + r) * Nc + n0 + c];
  }
  __syncthreads();
#pragma unroll
  for (int i = 0; i < 16; ++i) {
    int r = rr * 16 + i;
    out[(size_t)(n0 + r) * 512 + k0 + c] = t[c][r];
  }
}

// int32 mask [4096][4096] -> PERMUTED bit mask [4096][64] u64.
// Lane l ballots column kvp(l) so the two mask bits of each packed-bf16 pair
// (pa elements 2w,2w+1) sit 16 bits apart:
//   mt bit l  <->  kv = 32*l5 | 16*l1 | (l3:2)*4 | 2*l0 | l4
__global__ __launch_bounds__(256) void k_maskbits(const int* __restrict__ mask,
                                                  u64* __restrict__ bits) {
  int row = blockIdx.x;
  int l = threadIdx.x & 63, w = threadIdx.x >> 6;
  const int jj = l >> 5, odd = (l >> 4) & 1, gg = (l >> 2) & 3, wb = l & 3;
  const int kvp = 32 * jj + 16 * (wb >> 1) + 4 * gg + 2 * (wb & 1) + odd;
  const int* mr = mask + (size_t)row * NSEQ;
  for (int t = w; t < 64; t += 4) {
    u64 b = __ballot(mr[t * 64 + kvp] != 0);
    if (l == 0) bits[(size_t)row * 64 + t] = b;
  }
}

// ---------------- shared GEMM main loop (m97-style, swizzled gload_lds) ----------------
__device__ __forceinline__ void gemm_mainloop(const __bf16* __restrict__ A,
                                              const __bf16* __restrict__ Bt,
                                              int m0, int n0,
                                              __bf16* As, __bf16* Bs,
                                              f32x4 acc[4][4]) {
  const int tid = threadIdx.x, l = tid & 63, w = tid >> 6;
  const int wr = w >> 1, wc = w & 1;
  for (int kt = 0; kt < DIMQ; kt += 64) {
    __syncthreads();
#pragma unroll
    for (int it = 0; it < 4; ++it) {
      int c = it * 256 + tid;
      int row = c >> 3, j = c & 7, js = j ^ (row & 7);
      gload16(As + (size_t)(it * 256 + w * 64) * 8,
              A + (size_t)(m0 + row) * DIMQ + kt + js * 8);
      gload16(Bs + (size_t)(it * 256 + w * 64) * 8,
              Bt + (size_t)(n0 + row) * DIMQ + kt + js * 8);
    }
    __syncthreads();
#pragma unroll
    for (int kk = 0; kk < 2; ++kk) {
      bf16x8 a[4], b[4];
#pragma unroll
      for (int mt = 0; mt < 4; ++mt) {
        int row = wr * 64 + mt * 16 + (l & 15);
        int g = (kk * 4 + (l >> 4)) ^ (row & 7);
        a[mt] = *reinterpret_cast<const bf16x8*>((const char*)As + row * 128 + g * 16);
      }
#pragma unroll
      for (int nt = 0; nt < 4; ++nt) {
        int row = wc * 64 + nt * 16 + (l & 15);
        int g = (kk * 4 + (l >> 4)) ^ (row & 7);
        b[nt] = *reinterpret_cast<const bf16x8*>((const char*)Bs + row * 128 + g * 16);
      }
#pragma unroll
      for (int mt = 0; mt < 4; ++mt)
#pragma unroll
        for (int nt = 0; nt < 4; ++nt)
          acc[mt][nt] = __builtin_amdgcn_mfma_f32_16x16x32_bf16(a[mt], b[nt], acc[mt][nt], 0, 0, 0);
    }
  }
}

// ---------------- QKV GEMM (1D grid, XCD-pinned m-panels; Q pre-scaled; V k-permuted) ----------------
__global__ __launch_bounds__(256) void k_gemm_qkv(const __bf16* __restrict__ A,
                                                  const __bf16* __restrict__ Bt,
                                                  __bf16* __restrict__ Qh,
                                                  __bf16* __restrict__ Kh,
                                                  __bf16* __restrict__ VT) {
  __shared__ __bf16 As[128 * 64], Bs[128 * 64];
  f32x4 acc[4][4] = {};
  const int l = threadIdx.x & 63, w = threadIdx.x >> 6, wr = w >> 1, wc = w & 1;
  // 768 blocks: xcd = bid&7 owns m-tiles xcd*8..xcd*8+7 (same-m blocks share L2)
  const int bid = blockIdx.x;
  const int xcd = bid & 7, local = bid >> 3;          // local: 0..95
  const int m0 = (xcd * 8 + local / 12) * 128;
  const int n0 = (local % 12) * 128;
  gemm_mainloop(A, Bt, m0, n0, As, Bs, acc);
#pragma unroll
  for (int nt = 0; nt < 4; ++nt) {
    int n = n0 + wc * 64 + nt * 16 + (l & 15);
    int sec = n >> 9;           // 0=q 1=k 2=v
    int hh = (n >> 5) & 15;     // head
    int d = n & 31;             // dim in head
#pragma unroll
    for (int mt = 0; mt < 4; ++mt) {
      int m = m0 + wr * 64 + mt * 16 + (l >> 4) * 4;
      int bb = m >> 12, nn = m & 4095;
      size_t bh = (size_t)bb * NHEAD + hh;
      f32x4 v = acc[mt][nt];
      if (sec == 0) {
        __bf16* p = Qh + (bh * NSEQ + nn) * HDIM + d;
        p[0] = (__bf16)(v[0] * C2F); p[HDIM] = (__bf16)(v[1] * C2F);
        p[2 * HDIM] = (__bf16)(v[2] * C2F); p[3 * HDIM] = (__bf16)(v[3] * C2F);
      } else if (sec == 1) {
        __bf16* p = Kh + (bh * NSEQ + nn) * HDIM + d;
        p[0] = (__bf16)v[0]; p[HDIM] = (__bf16)v[1];
        p[2 * HDIM] = (__bf16)v[2]; p[3 * HDIM] = (__bf16)v[3];
      } else {
        // k-permuted V: within each 32-kv group, low5 = hi*16 + g*4 + r -> g*8 + hi*4 + r
        int low = nn & 31;
        int nnp = (nn & ~31) | (((low >> 2) & 3) << 3) | (((low >> 4) & 1) << 2);
        bf16x4 o;
        o.x = (__bf16)v[0]; o.y = (__bf16)v[1]; o.z = (__bf16)v[2]; o.w = (__bf16)v[3];
        *reinterpret_cast<bf16x4*>(VT + (bh * HDIM + d) * NSEQ + nnp) = o;
      }
    }
  }
}

// ---------------- fused masked attention, v14: v12 math (scalar casts), XCD grids kept ----------------
__device__ __forceinline__ void attn_compute(const __bf16* __restrict__ Kl,
                                             const __bf16* __restrict__ Vl,
                                             const bf16x8 qf[2], u64 mw0, u64 mw1,
                                             f32x4 acc[2][2], f32x4 accS[2],
                                             int kOff, const int vOff[2][2],
                                             bf16x8 ones, int g) {
  bf16x8 kf[4];
#pragma unroll
  for (int f = 0; f < 4; ++f)
    kf[f] = *reinterpret_cast<const bf16x8*>(Kl + kOff + f * 512);

  bf16x8 vvb[2][2];  // [jj][dt], single b128 each
#pragma unroll
  for (int jj = 0; jj < 2; ++jj)
#pragma unroll
    for (int dt = 0; dt < 2; ++dt)
      vvb[jj][dt] = *reinterpret_cast<const bf16x8*>(Vl + vOff[jj][dt]);

  const f32x4 z4 = {0.f, 0.f, 0.f, 0.f};
#pragma unroll
  for (int rt = 0; rt < 2; ++rt) {
    const u64 mw = rt ? mw1 : mw0;
#pragma unroll
    for (int jj = 0; jj < 2; ++jj) {
      // S^T for kv halves f=2jj, 2jj+1: lane holds q=q16, k=16f+4g+r
      f32x4 s0 = __builtin_amdgcn_mfma_f32_16x16x32_bf16(kf[2 * jj], qf[rt], z4, 0, 0, 0);
      f32x4 s1 = __builtin_amdgcn_mfma_f32_16x16x32_bf16(kf[2 * jj + 1], qf[rt], z4, 0, 0, 0);
      bf16x8 pa;  // k order e = hi*4 + r matches permuted-V b128 order
#pragma unroll
      for (int r = 0; r < 4; ++r) {
        pa[r] = (__bf16)fast_exp2(s0[r]);
        pa[r + 4] = (__bf16)fast_exp2(s1[r]);
      }
      const u32 x = ((u32)(mw >> (32 * jj))) >> (g * 4);
      u32x4 pw = __builtin_bit_cast(u32x4, pa);
#pragma unroll
      for (int wq = 0; wq < 4; ++wq) {
        u32 zb = (x >> wq) & 0x10001u;
        pw[wq] &= (zb << 16) - zb;  // 0 / 0xFFFF / 0xFFFF0000 / 0xFFFFFFFF
      }
      bf16x8 pm = __builtin_bit_cast(bf16x8, pw);
      accS[rt] = __builtin_amdgcn_mfma_f32_16x16x32_bf16(pm, ones, accS[rt], 0, 0, 0);
#pragma unroll
      for (int dt = 0; dt < 2; ++dt)
        acc[rt][dt] =
            __builtin_amdgcn_mfma_f32_16x16x32_bf16(pm, vvb[jj][dt], acc[rt][dt], 0, 0, 0);
    }
  }
}

__global__ __launch_bounds__(256, 4) void k_attn(const __bf16* __restrict__ Qh,
                                                 const __bf16* __restrict__ Kh,
                                                 const __bf16* __restrict__ VT,
                                                 const u64* __restrict__ mbits,
                                                 float* __restrict__ Opart,
                                                 float* __restrict__ Lpart) {
  __shared__ __bf16 Klds[2][2][2048];  // [buf][pair][64 rows x 4 slots], slot-swizzled
  __shared__ __bf16 Vlds[2][2][2048];  // [buf][pair][32 d x 8 granules], granule-swizzled
  const int tid = threadIdx.x;
  const int l = tid & 63, w = tid >> 6;
  const int g = l >> 4, q16 = l & 15;
  const int bid = blockIdx.x;
  const int sp = bid >> 10;                          // kv split: 0 or 1
  const int rest = bid & 1023;
  const int bh = (rest & 7) * 4 + ((rest >> 3) & 3); // XCD-aware decode
  const int qx = rest >> 5;                          // 0..31
  const int q0 = qx * 128 + w * 32;
  const int base = sp * 32;                          // kv tile range [base, base+32)
  const __bf16* Qb = Qh + (size_t)bh * NSEQ * HDIM;
  const __bf16* Kb = Kh + (size_t)bh * NSEQ * HDIM;
  const __bf16* Vb = VT + (size_t)bh * HDIM * NSEQ;  // [32 d][4096 kp]
  const u64* mr0 = mbits + (size_t)(q0 + q16) * 64;
  const u64* mr1 = mbits + (size_t)(q0 + 16 + q16) * 64;

  // staging sources (pre-swizzled: linear LDS dest + swizzled read match)
  const int rk = tid >> 2, gsK = (tid & 3) ^ ((rk >> 1) & 3);
  const __bf16* srcK = Kb + (size_t)rk * HDIM + gsK * 8;   // += t*2048
  const int dv = tid >> 3, gv = (tid & 7) ^ (dv & 7);
  const __bf16* srcV = Vb + (size_t)dv * NSEQ + gv * 8;    // += t*64

  // LDS read offsets (loop-invariant, elements)
  const int kOff = q16 * 32 + (g ^ ((q16 >> 1) & 3)) * 8;
  int vOff[2][2];
#pragma unroll
  for (int jj = 0; jj < 2; ++jj)
#pragma unroll
    for (int dt = 0; dt < 2; ++dt) {
      int d = dt * 16 + q16;
      vOff[jj][dt] = d * 64 + ((4 * jj + g) ^ (d & 7)) * 8;
    }

  bf16x8 qf[2];
#pragma unroll
  for (int rt = 0; rt < 2; ++rt)
    qf[rt] = *reinterpret_cast<const bf16x8*>(
        Qb + (size_t)(q0 + rt * 16 + q16) * HDIM + g * 8);

  bf16x8 ones;
#pragma unroll
  for (int e = 0; e < 8; ++e) ones[e] = (__bf16)1.0f;

  f32x4 acc[2][2] = {};
  f32x4 accS[2] = {};

  // prologue: stage tiles base, base+1 into buf0 (pairs 0,1); wide mask loads
  gload16(&Klds[0][0][0] + tid * 8, srcK + (size_t)base * 2048);
  gload16(&Vlds[0][0][0] + tid * 8, srcV + (size_t)base * 64);
  gload16(&Klds[0][1][0] + tid * 8, srcK + (size_t)(base + 1) * 2048);
  gload16(&Vlds[0][1][0] + tid * 8, srcV + (size_t)(base + 1) * 64);
  u64 a0, a1, a2, a3, b0, b1, b2, b3;
  {
    ulonglong2 m0v = *reinterpret_cast<const ulonglong2*>(mr0 + base);
    ulonglong2 m1v = *reinterpret_cast<const ulonglong2*>(mr1 + base);
    a0 = m0v.x; a2 = m0v.y; a1 = m1v.x; a3 = m1v.y;
  }
  __syncthreads();

  for (int t = base; t < base + 32; t += 4) {
    // phase A: stage t+2,t+3 -> buf1; compute t,t+1 from buf0
    gload16(&Klds[1][0][0] + tid * 8, srcK + (size_t)(t + 2) * 2048);
    gload16(&Vlds[1][0][0] + tid * 8, srcV + (size_t)(t + 2) * 64);
    gload16(&Klds[1][1][0] + tid * 8, srcK + (size_t)(t + 3) * 2048);
    gload16(&Vlds[1][1][0] + tid * 8, srcV + (size_t)(t + 3) * 64);
    {
      ulonglong2 m0v = *reinterpret_cast<const ulonglong2*>(mr0 + t + 2);
      ulonglong2 m1v = *reinterpret_cast<const ulonglong2*>(mr1 + t + 2);
      b0 = m0v.x; b2 = m0v.y; b1 = m1v.x; b3 = m1v.y;
    }
    attn_compute(&Klds[0][0][0], &Vlds[0][0][0], qf, a0, a1, acc, accS, kOff, vOff, ones, g);
    attn_compute(&Klds[0][1][0], &Vlds[0][1][0], qf, a2, a3, acc, accS, kOff, vOff, ones, g);
    __syncthreads();
    // phase B: stage t+4,t+5 (clamped) -> buf0; compute t+2,t+3 from buf1
    const int t4 = (t + 4 < base + 32) ? t + 4 : base + 30;
    gload16(&Klds[0][0][0] + tid * 8, srcK + (size_t)t4 * 2048);
    gload16(&Vlds[0][0][0] + tid * 8, srcV + (size_t)t4 * 64);
    gload16(&Klds[0][1][0] + tid * 8, srcK + (size_t)(t4 + 1) * 2048);
    gload16(&Vlds[0][1][0] + tid * 8, srcV + (size_t)(t4 + 1) * 64);
    {
      ulonglong2 m0v = *reinterpret_cast<const ulonglong2*>(mr0 + t4);
      ulonglong2 m1v = *reinterpret_cast<const ulonglong2*>(mr1 + t4);
      a0 = m0v.x; a2 = m0v.y; a1 = m1v.x; a3 = m1v.y;
    }
    attn_compute(&Klds[1][0][0], &Vlds[1][0][0], qf, b0, b1, acc, accS, kOff, vOff, ones, g);
    attn_compute(&Klds[1][1][0], &Vlds[1][1][0], qf, b2, b3, acc, accS, kOff, vOff, ones, g);
    __syncthreads();
  }

  const int bb = bh >> 4, hh = bh & 15;
  float* Op = Opart + (size_t)sp * 8192 * 512;
  float* Lp = Lpart + (size_t)sp * 32 * 4096;
#pragma unroll
  for (int rt = 0; rt < 2; ++rt)
#pragma unroll
    for (int r = 0; r < 4; ++r) {
      int qrow = q0 + rt * 16 + g * 4 + r;
      if (q16 == 0) Lp[(size_t)bh * 4096 + qrow] = accS[rt][r];
#pragma unroll
      for (int dt = 0; dt < 2; ++dt)
        Op[((size_t)bb * NSEQ + qrow) * DIMQ + hh * HDIM + dt * 16 + q16] =
            acc[rt][dt][r];
    }
}

// ---------------- output projection GEMM, fused with split-combine ----------------
// 1D grid 256, XCD-pinned m-panels. A[m][k] = (Op0+Op1)/(L0+L1), built in-register
// and ds_written to the SAME swizzled LDS slot gload16 uses. B via gload16.
__global__ __launch_bounds__(256) void k_gemm_proj(const float* __restrict__ Op,
                                                   const float* __restrict__ Lp,
                                                   const __bf16* __restrict__ Bt,
                                                   float* __restrict__ Out) {
  __shared__ __bf16 As[128 * 64], Bs[128 * 64];
  f32x4 acc[4][4] = {};
  const int tid = threadIdx.x;
  const int l = tid & 63, w = tid >> 6, wr = w >> 1, wc = w & 1;
  const int bid = blockIdx.x;
  const int xcd = bid & 7, local = bid >> 3;          // local: 0..31
  const int m0 = (xcd * 8 + (local >> 2)) * 128;
  const int n0 = (local & 3) * 128;
  for (int kt = 0; kt < DIMQ; kt += 64) {
    __syncthreads();
#pragma unroll
    for (int it = 0; it < 4; ++it) {
      int c = it * 256 + tid;
      int row = c >> 3, j = c & 7, js = j ^ (row & 7);
      int m = m0 + row, col = kt + js * 8;
      const float* p0 = Op + (size_t)m * DIMQ + col;
      const float* p1 = p0 + (size_t)8192 * 512;
      float4 x0 = *reinterpret_cast<const float4*>(p0);
      float4 x1 = *reinterpret_cast<const float4*>(p0 + 4);
      float4 y0 = *reinterpret_cast<const float4*>(p1);
      float4 y1 = *reinterpret_cast<const float4*>(p1 + 4);
      const int bb = m >> 12, nn = m & 4095, hh = col >> 5;
      const size_t li = ((size_t)(bb * 16 + hh)) * 4096 + nn;
      float inv = 1.f / (Lp[li] + Lp[(size_t)32 * 4096 + li]);
      bf16x8 av;
      av[0] = (__bf16)((x0.x + y0.x) * inv);
      av[1] = (__bf16)((x0.y + y0.y) * inv);
      av[2] = (__bf16)((x0.z + y0.z) * inv);
      av[3] = (__bf16)((x0.w + y0.w) * inv);
      av[4] = (__bf16)((x1.x + y1.x) * inv);
      av[5] = (__bf16)((x1.y + y1.y) * inv);
      av[6] = (__bf16)((x1.z + y1.z) * inv);
      av[7] = (__bf16)((x1.w + y1.w) * inv);
      *reinterpret_cast<bf16x8*>(As + (size_t)c * 8) = av;
      gload16(Bs + (size_t)(it * 256 + w * 64) * 8,
              Bt + (size_t)(n0 + row) * DIMQ + kt + js * 8);
    }
    __syncthreads();
#pragma unroll
    for (int kk = 0; kk < 2; ++kk) {
      bf16x8 a[4], b[4];
#pragma unroll
      for (int mt = 0; mt < 4; ++mt) {
        int row = wr * 64 + mt * 16 + (l & 15);
        int g = (kk * 4 + (l >> 4)) ^ (row & 7);
        a[mt] = *reinterpret_cast<const bf16x8*>((const char*)As + row * 128 + g * 16);
      }
#pragma unroll
      for (int nt = 0; nt < 4; ++nt) {
        int row = wc * 64 + nt * 16 + (l & 15);
        int g = (kk * 4 + (l >> 4)) ^ (row & 7);
        b[nt] = *reinterpret_cast<const bf16x8*>((const char*)Bs + row * 128 + g * 16);
      }
#pragma unroll
      for (int mt = 0; mt < 4; ++mt)
#pragma unroll
        for (int nt = 0; nt < 4; ++nt)
          acc[mt][nt] = __builtin_amdgcn_mfma_f32_16x16x32_bf16(a[mt], b[nt], acc[mt][nt], 0, 0, 0);
    }
  }
#pragma unroll
  for (int nt = 0; nt < 4; ++nt) {
    int n = n0 + wc * 64 + nt * 16 + (l & 15);
#pragma unroll
    for (int mt = 0; mt < 4; ++mt) {
      int m = m0 + wr * 64 + mt * 16 + (l >> 4) * 4;
      f32x4 v = acc[mt][nt];
      float* p = Out + (size_t)m * DIMQ + n;
      p[0] = v[0]; p[DIMQ] = v[1];
      p[2 * DIMQ] = v[2]; p[3 * DIMQ] = v[3];
    }
  }
}

// ---------------- launcher ----------------
extern "C" void kernel_launch(void* const* d_in, const int* in_sizes, int n_in,
                              void* d_out, int out_size, void* d_ws, size_t ws_size,
                              hipStream_t stream) {
  (void)in_sizes; (void)n_in; (void)out_size; (void)ws_size;
  const float* batch  = (const float*)d_in[0];
  const float* w_qkv  = (const float*)d_in[1];
  const float* w_proj = (const float*)d_in[2];
  const int*   cmask  = (const int*)d_in[3];

  __bf16* Abf = (__bf16*)d_ws;                       // 8192*512 bf16      (8 MB)
  __bf16* WqT = Abf + (size_t)8192 * 512;            // 1536*512           (1.5 MB)
  __bf16* WpT = WqT + (size_t)1536 * 512;            // 512*512            (0.5 MB)
  u64*    mb  = (u64*)(WpT + (size_t)512 * 512);     // 4096*64 u64        (2 MB)
  __bf16* Qh  = (__bf16*)(mb + (size_t)4096 * 64);   // 32*4096*32         (8 MB)
  __bf16* Kh  = Qh + (size_t)32 * NSEQ * HDIM;       //                    (8 MB)
  __bf16* VT  = Kh + (size_t)32 * NSEQ * HDIM;       //                    (8 MB)
  float*  Opart = (float*)(VT + (size_t)32 * NSEQ * HDIM); // 2 x 16 MB
  float*  Lpart = Opart + (size_t)2 * 8192 * 512;          // 2 x 0.5 MB

  k_cvt_bf16<<<4096, 256, 0, stream>>>(batch, Abf);
  k_cvtT<<<dim3(24, 8), 256, 0, stream>>>(w_qkv, WqT, 1536);
  k_cvtT<<<dim3(8, 8), 256, 0, stream>>>(w_proj, WpT, 512);
  k_maskbits<<<4096, 256, 0, stream>>>(cmask, mb);
  k_gemm_qkv<<<768, 256, 0, stream>>>(Abf, WqT, Qh, Kh, VT);
  k_attn<<<2048, 256, 0, stream>>>(Qh, Kh, VT, mb, Opart, Lpart);
  k_gemm_proj<<<256, 256, 0, stream>>>(Opart, Lpart, WpT, (float*)d_out);
}

// Round 18
// 191.939 us; speedup vs baseline: 1.3633x; 1.0427x over previous
//
#include <hip/hip_runtime.h>
#include <hip/hip_bf16.h>

typedef __attribute__((ext_vector_type(4))) float f32x4;
typedef __attribute__((ext_vector_type(8))) __bf16 bf16x8;
typedef __attribute__((ext_vector_type(4))) __bf16 bf16x4;
typedef __attribute__((ext_vector_type(4))) unsigned int u32x4;
typedef unsigned long long u64;
typedef unsigned int u32;

#define DIMQ 512
#define NSEQ 4096
#define NHEAD 16
#define HDIM 32
#define SCALE_QK 0.17677669529663687f
#define C2F (SCALE_QK * 1.4426950408889634f)  // scale * log2(e), folded into Q

__device__ __forceinline__ void gload16(void* lds, const void* g) {
  __builtin_amdgcn_global_load_lds(
      (const __attribute__((address_space(1))) void*)g,
      (__attribute__((address_space(3))) void*)lds, 16, 0, 0);
}

// raw v_exp_f32: args are statically bounded (|x| <= ~52), masked lanes are
// AND-zeroed afterward, so no ocml denormal/range fixup is needed.
__device__ __forceinline__ float fast_exp2(float x) {
#if __has_builtin(__builtin_amdgcn_exp2f)
  return __builtin_amdgcn_exp2f(x);
#else
  float r;
  asm("v_exp_f32 %0, %1" : "=v"(r) : "v"(x));
  return r;
#endif
}

// ---------------- conversion kernels ----------------

__global__ __launch_bounds__(256) void k_cvt_bf16(const float* __restrict__ in,
                                                  __bf16* __restrict__ out) {
  int i = blockIdx.x * 256 + threadIdx.x;
  float4 v = reinterpret_cast<const float4*>(in)[i];
  bf16x4 o;
  o.x = (__bf16)v.x; o.y = (__bf16)v.y; o.z = (__bf16)v.z; o.w = (__bf16)v.w;
  reinterpret_cast<bf16x4*>(out)[i] = o;
}

// in: fp32 [512][Nc]  ->  out: bf16 [Nc][512]  (transpose via LDS tile)
__global__ __launch_bounds__(256) void k_cvtT(const float* __restrict__ in,
                                              __bf16* __restrict__ out, int Nc) {
  __shared__ __bf16 t[64][72];
  int k0 = blockIdx.y * 64, n0 = blockIdx.x * 64;
  int c = threadIdx.x & 63, rr = threadIdx.x >> 6;
#pragma unroll
  for (int i = 0; i < 16; ++i) {
    int r = rr * 16 + i;
    t[r][c] = (__bf16)in[(size_t)(k0 + r) * Nc + n0 + c];
  }
  __syncthreads();
#pragma unroll
  for (int i = 0; i < 16; ++i) {
    int r = rr * 16 + i;
    out[(size_t)(n0 + r) * 512 + k0 + c] = t[c][r];
  }
}

// int32 mask [4096][4096] -> PERMUTED bit mask [4096][64] u64.
// Lane l ballots column kvp(l) so the two mask bits of each packed-bf16 pair
// (pa elements 2w,2w+1) sit 16 bits apart:
//   mt bit l  <->  kv = 32*l5 | 16*l1 | (l3:2)*4 | 2*l0 | l4
__global__ __launch_bounds__(256) void k_maskbits(const int* __restrict__ mask,
                                                  u64* __restrict__ bits) {
  int row = blockIdx.x;
  int l = threadIdx.x & 63, w = threadIdx.x >> 6;
  const int jj = l >> 5, odd = (l >> 4) & 1, gg = (l >> 2) & 3, wb = l & 3;
  const int kvp = 32 * jj + 16 * (wb >> 1) + 4 * gg + 2 * (wb & 1) + odd;
  const int* mr = mask + (size_t)row * NSEQ;
  for (int t = w; t < 64; t += 4) {
    u64 b = __ballot(mr[t * 64 + kvp] != 0);
    if (l == 0) bits[(size_t)row * 64 + t] = b;
  }
}

// ---------------- shared GEMM main loop (m97-style, swizzled gload_lds) ----------------
__device__ __forceinline__ void gemm_mainloop(const __bf16* __restrict__ A,
                                              const __bf16* __restrict__ Bt,
                                              int m0, int n0,
                                              __bf16* As, __bf16* Bs,
                                              f32x4 acc[4][4]) {
  const int tid = threadIdx.x, l = tid & 63, w = tid >> 6;
  const int wr = w >> 1, wc = w & 1;
  for (int kt = 0; kt < DIMQ; kt += 64) {
    __syncthreads();
#pragma unroll
    for (int it = 0; it < 4; ++it) {
      int c = it * 256 + tid;
      int row = c >> 3, j = c & 7, js = j ^ (row & 7);
      gload16(As + (size_t)(it * 256 + w * 64) * 8,
              A + (size_t)(m0 + row) * DIMQ + kt + js * 8);
      gload16(Bs + (size_t)(it * 256 + w * 64) * 8,
              Bt + (size_t)(n0 + row) * DIMQ + kt + js * 8);
    }
    __syncthreads();
#pragma unroll
    for (int kk = 0; kk < 2; ++kk) {
      bf16x8 a[4], b[4];
#pragma unroll
      for (int mt = 0; mt < 4; ++mt) {
        int row = wr * 64 + mt * 16 + (l & 15);
        int g = (kk * 4 + (l >> 4)) ^ (row & 7);
        a[mt] = *reinterpret_cast<const bf16x8*>((const char*)As + row * 128 + g * 16);
      }
#pragma unroll
      for (int nt = 0; nt < 4; ++nt) {
        int row = wc * 64 + nt * 16 + (l & 15);
        int g = (kk * 4 + (l >> 4)) ^ (row & 7);
        b[nt] = *reinterpret_cast<const bf16x8*>((const char*)Bs + row * 128 + g * 16);
      }
#pragma unroll
      for (int mt = 0; mt < 4; ++mt)
#pragma unroll
        for (int nt = 0; nt < 4; ++nt)
          acc[mt][nt] = __builtin_amdgcn_mfma_f32_16x16x32_bf16(a[mt], b[nt], acc[mt][nt], 0, 0, 0);
    }
  }
}

// ---------------- QKV GEMM (1D grid, XCD-pinned m-panels; Q pre-scaled; V k-permuted) ----------------
__global__ __launch_bounds__(256) void k_gemm_qkv(const __bf16* __restrict__ A,
                                                  const __bf16* __restrict__ Bt,
                                                  __bf16* __restrict__ Qh,
                                                  __bf16* __restrict__ Kh,
                                                  __bf16* __restrict__ VT) {
  __shared__ __bf16 As[128 * 64], Bs[128 * 64];
  f32x4 acc[4][4] = {};
  const int l = threadIdx.x & 63, w = threadIdx.x >> 6, wr = w >> 1, wc = w & 1;
  // 768 blocks: xcd = bid&7 owns m-tiles xcd*8..xcd*8+7 (same-m blocks share L2)
  const int bid = blockIdx.x;
  const int xcd = bid & 7, local = bid >> 3;          // local: 0..95
  const int m0 = (xcd * 8 + local / 12) * 128;
  const int n0 = (local % 12) * 128;
  gemm_mainloop(A, Bt, m0, n0, As, Bs, acc);
#pragma unroll
  for (int nt = 0; nt < 4; ++nt) {
    int n = n0 + wc * 64 + nt * 16 + (l & 15);
    int sec = n >> 9;           // 0=q 1=k 2=v
    int hh = (n >> 5) & 15;     // head
    int d = n & 31;             // dim in head
#pragma unroll
    for (int mt = 0; mt < 4; ++mt) {
      int m = m0 + wr * 64 + mt * 16 + (l >> 4) * 4;
      int bb = m >> 12, nn = m & 4095;
      size_t bh = (size_t)bb * NHEAD + hh;
      f32x4 v = acc[mt][nt];
      if (sec == 0) {
        __bf16* p = Qh + (bh * NSEQ + nn) * HDIM + d;
        p[0] = (__bf16)(v[0] * C2F); p[HDIM] = (__bf16)(v[1] * C2F);
        p[2 * HDIM] = (__bf16)(v[2] * C2F); p[3 * HDIM] = (__bf16)(v[3] * C2F);
      } else if (sec == 1) {
        __bf16* p = Kh + (bh * NSEQ + nn) * HDIM + d;
        p[0] = (__bf16)v[0]; p[HDIM] = (__bf16)v[1];
        p[2 * HDIM] = (__bf16)v[2]; p[3 * HDIM] = (__bf16)v[3];
      } else {
        // k-permuted V: within each 32-kv group, low5 = hi*16 + g*4 + r -> g*8 + hi*4 + r
        int low = nn & 31;
        int nnp = (nn & ~31) | (((low >> 2) & 3) << 3) | (((low >> 4) & 1) << 2);
        bf16x4 o;
        o.x = (__bf16)v[0]; o.y = (__bf16)v[1]; o.z = (__bf16)v[2]; o.w = (__bf16)v[3];
        *reinterpret_cast<bf16x4*>(VT + (bh * HDIM + d) * NSEQ + nnp) = o;
      }
    }
  }
}

// ---------------- fused masked attention, v15: v14 + T5 setprio around MFMA cluster ----------------
__device__ __forceinline__ void attn_compute(const __bf16* __restrict__ Kl,
                                             const __bf16* __restrict__ Vl,
                                             const bf16x8 qf[2], u64 mw0, u64 mw1,
                                             f32x4 acc[2][2], f32x4 accS[2],
                                             int kOff, const int vOff[2][2],
                                             bf16x8 ones, int g) {
  bf16x8 kf[4];
#pragma unroll
  for (int f = 0; f < 4; ++f)
    kf[f] = *reinterpret_cast<const bf16x8*>(Kl + kOff + f * 512);

  bf16x8 vvb[2][2];  // [jj][dt], single b128 each
#pragma unroll
  for (int jj = 0; jj < 2; ++jj)
#pragma unroll
    for (int dt = 0; dt < 2; ++dt)
      vvb[jj][dt] = *reinterpret_cast<const bf16x8*>(Vl + vOff[jj][dt]);

  const f32x4 z4 = {0.f, 0.f, 0.f, 0.f};
#pragma unroll
  for (int rt = 0; rt < 2; ++rt) {
    const u64 mw = rt ? mw1 : mw0;
#pragma unroll
    for (int jj = 0; jj < 2; ++jj) {
      // S^T for kv halves f=2jj, 2jj+1: lane holds q=q16, k=16f+4g+r
      __builtin_amdgcn_s_setprio(1);
      f32x4 s0 = __builtin_amdgcn_mfma_f32_16x16x32_bf16(kf[2 * jj], qf[rt], z4, 0, 0, 0);
      f32x4 s1 = __builtin_amdgcn_mfma_f32_16x16x32_bf16(kf[2 * jj + 1], qf[rt], z4, 0, 0, 0);
      __builtin_amdgcn_s_setprio(0);
      bf16x8 pa;  // k order e = hi*4 + r matches permuted-V b128 order
#pragma unroll
      for (int r = 0; r < 4; ++r) {
        pa[r] = (__bf16)fast_exp2(s0[r]);
        pa[r + 4] = (__bf16)fast_exp2(s1[r]);
      }
      const u32 x = ((u32)(mw >> (32 * jj))) >> (g * 4);
      u32x4 pw = __builtin_bit_cast(u32x4, pa);
#pragma unroll
      for (int wq = 0; wq < 4; ++wq) {
        u32 zb = (x >> wq) & 0x10001u;
        pw[wq] &= (zb << 16) - zb;  // 0 / 0xFFFF / 0xFFFF0000 / 0xFFFFFFFF
      }
      bf16x8 pm = __builtin_bit_cast(bf16x8, pw);
      __builtin_amdgcn_s_setprio(1);
      accS[rt] = __builtin_amdgcn_mfma_f32_16x16x32_bf16(pm, ones, accS[rt], 0, 0, 0);
#pragma unroll
      for (int dt = 0; dt < 2; ++dt)
        acc[rt][dt] =
            __builtin_amdgcn_mfma_f32_16x16x32_bf16(pm, vvb[jj][dt], acc[rt][dt], 0, 0, 0);
      __builtin_amdgcn_s_setprio(0);
    }
  }
}

__global__ __launch_bounds__(256, 4) void k_attn(const __bf16* __restrict__ Qh,
                                                 const __bf16* __restrict__ Kh,
                                                 const __bf16* __restrict__ VT,
                                                 const u64* __restrict__ mbits,
                                                 float* __restrict__ Opart,
                                                 float* __restrict__ Lpart) {
  __shared__ __bf16 Klds[2][2][2048];  // [buf][pair][64 rows x 4 slots], slot-swizzled
  __shared__ __bf16 Vlds[2][2][2048];  // [buf][pair][32 d x 8 granules], granule-swizzled
  const int tid = threadIdx.x;
  const int l = tid & 63, w = tid >> 6;
  const int g = l >> 4, q16 = l & 15;
  const int bid = blockIdx.x;
  const int sp = bid >> 10;                          // kv split: 0 or 1
  const int rest = bid & 1023;
  const int bh = (rest & 7) * 4 + ((rest >> 3) & 3); // XCD-aware decode
  const int qx = rest >> 5;                          // 0..31
  const int q0 = qx * 128 + w * 32;
  const int base = sp * 32;                          // kv tile range [base, base+32)
  const __bf16* Qb = Qh + (size_t)bh * NSEQ * HDIM;
  const __bf16* Kb = Kh + (size_t)bh * NSEQ * HDIM;
  const __bf16* Vb = VT + (size_t)bh * HDIM * NSEQ;  // [32 d][4096 kp]
  const u64* mr0 = mbits + (size_t)(q0 + q16) * 64;
  const u64* mr1 = mbits + (size_t)(q0 + 16 + q16) * 64;

  // staging sources (pre-swizzled: linear LDS dest + swizzled read match)
  const int rk = tid >> 2, gsK = (tid & 3) ^ ((rk >> 1) & 3);
  const __bf16* srcK = Kb + (size_t)rk * HDIM + gsK * 8;   // += t*2048
  const int dv = tid >> 3, gv = (tid & 7) ^ (dv & 7);
  const __bf16* srcV = Vb + (size_t)dv * NSEQ + gv * 8;    // += t*64

  // LDS read offsets (loop-invariant, elements)
  const int kOff = q16 * 32 + (g ^ ((q16 >> 1) & 3)) * 8;
  int vOff[2][2];
#pragma unroll
  for (int jj = 0; jj < 2; ++jj)
#pragma unroll
    for (int dt = 0; dt < 2; ++dt) {
      int d = dt * 16 + q16;
      vOff[jj][dt] = d * 64 + ((4 * jj + g) ^ (d & 7)) * 8;
    }

  bf16x8 qf[2];
#pragma unroll
  for (int rt = 0; rt < 2; ++rt)
    qf[rt] = *reinterpret_cast<const bf16x8*>(
        Qb + (size_t)(q0 + rt * 16 + q16) * HDIM + g * 8);

  bf16x8 ones;
#pragma unroll
  for (int e = 0; e < 8; ++e) ones[e] = (__bf16)1.0f;

  f32x4 acc[2][2] = {};
  f32x4 accS[2] = {};

  // prologue: stage tiles base, base+1 into buf0 (pairs 0,1); wide mask loads
  gload16(&Klds[0][0][0] + tid * 8, srcK + (size_t)base * 2048);
  gload16(&Vlds[0][0][0] + tid * 8, srcV + (size_t)base * 64);
  gload16(&Klds[0][1][0] + tid * 8, srcK + (size_t)(base + 1) * 2048);
  gload16(&Vlds[0][1][0] + tid * 8, srcV + (size_t)(base + 1) * 64);
  u64 a0, a1, a2, a3, b0, b1, b2, b3;
  {
    ulonglong2 m0v = *reinterpret_cast<const ulonglong2*>(mr0 + base);
    ulonglong2 m1v = *reinterpret_cast<const ulonglong2*>(mr1 + base);
    a0 = m0v.x; a2 = m0v.y; a1 = m1v.x; a3 = m1v.y;
  }
  __syncthreads();

  for (int t = base; t < base + 32; t += 4) {
    // phase A: stage t+2,t+3 -> buf1; compute t,t+1 from buf0
    gload16(&Klds[1][0][0] + tid * 8, srcK + (size_t)(t + 2) * 2048);
    gload16(&Vlds[1][0][0] + tid * 8, srcV + (size_t)(t + 2) * 64);
    gload16(&Klds[1][1][0] + tid * 8, srcK + (size_t)(t + 3) * 2048);
    gload16(&Vlds[1][1][0] + tid * 8, srcV + (size_t)(t + 3) * 64);
    {
      ulonglong2 m0v = *reinterpret_cast<const ulonglong2*>(mr0 + t + 2);
      ulonglong2 m1v = *reinterpret_cast<const ulonglong2*>(mr1 + t + 2);
      b0 = m0v.x; b2 = m0v.y; b1 = m1v.x; b3 = m1v.y;
    }
    attn_compute(&Klds[0][0][0], &Vlds[0][0][0], qf, a0, a1, acc, accS, kOff, vOff, ones, g);
    attn_compute(&Klds[0][1][0], &Vlds[0][1][0], qf, a2, a3, acc, accS, kOff, vOff, ones, g);
    __syncthreads();
    // phase B: stage t+4,t+5 (clamped) -> buf0; compute t+2,t+3 from buf1
    const int t4 = (t + 4 < base + 32) ? t + 4 : base + 30;
    gload16(&Klds[0][0][0] + tid * 8, srcK + (size_t)t4 * 2048);
    gload16(&Vlds[0][0][0] + tid * 8, srcV + (size_t)t4 * 64);
    gload16(&Klds[0][1][0] + tid * 8, srcK + (size_t)(t4 + 1) * 2048);
    gload16(&Vlds[0][1][0] + tid * 8, srcV + (size_t)(t4 + 1) * 64);
    {
      ulonglong2 m0v = *reinterpret_cast<const ulonglong2*>(mr0 + t4);
      ulonglong2 m1v = *reinterpret_cast<const ulonglong2*>(mr1 + t4);
      a0 = m0v.x; a2 = m0v.y; a1 = m1v.x; a3 = m1v.y;
    }
    attn_compute(&Klds[1][0][0], &Vlds[1][0][0], qf, b0, b1, acc, accS, kOff, vOff, ones, g);
    attn_compute(&Klds[1][1][0], &Vlds[1][1][0], qf, b2, b3, acc, accS, kOff, vOff, ones, g);
    __syncthreads();
  }

  const int bb = bh >> 4, hh = bh & 15;
  float* Op = Opart + (size_t)sp * 8192 * 512;
  float* Lp = Lpart + (size_t)sp * 32 * 4096;
#pragma unroll
  for (int rt = 0; rt < 2; ++rt)
#pragma unroll
    for (int r = 0; r < 4; ++r) {
      int qrow = q0 + rt * 16 + g * 4 + r;
      if (q16 == 0) Lp[(size_t)bh * 4096 + qrow] = accS[rt][r];
#pragma unroll
      for (int dt = 0; dt < 2; ++dt)
        Op[((size_t)bb * NSEQ + qrow) * DIMQ + hh * HDIM + dt * 16 + q16] =
            acc[rt][dt][r];
    }
}

// ---------------- output projection GEMM, fused with split-combine ----------------
// 1D grid 256, XCD-pinned m-panels. A[m][k] = (Op0+Op1)/(L0+L1), built in-register
// and ds_written to the SAME swizzled LDS slot gload16 uses. B via gload16.
__global__ __launch_bounds__(256) void k_gemm_proj(const float* __restrict__ Op,
                                                   const float* __restrict__ Lp,
                                                   const __bf16* __restrict__ Bt,
                                                   float* __restrict__ Out) {
  __shared__ __bf16 As[128 * 64], Bs[128 * 64];
  f32x4 acc[4][4] = {};
  const int tid = threadIdx.x;
  const int l = tid & 63, w = tid >> 6, wr = w >> 1, wc = w & 1;
  const int bid = blockIdx.x;
  const int xcd = bid & 7, local = bid >> 3;          // local: 0..31
  const int m0 = (xcd * 8 + (local >> 2)) * 128;
  const int n0 = (local & 3) * 128;
  for (int kt = 0; kt < DIMQ; kt += 64) {
    __syncthreads();
#pragma unroll
    for (int it = 0; it < 4; ++it) {
      int c = it * 256 + tid;
      int row = c >> 3, j = c & 7, js = j ^ (row & 7);
      int m = m0 + row, col = kt + js * 8;
      const float* p0 = Op + (size_t)m * DIMQ + col;
      const float* p1 = p0 + (size_t)8192 * 512;
      float4 x0 = *reinterpret_cast<const float4*>(p0);
      float4 x1 = *reinterpret_cast<const float4*>(p0 + 4);
      float4 y0 = *reinterpret_cast<const float4*>(p1);
      float4 y1 = *reinterpret_cast<const float4*>(p1 + 4);
      const int bb = m >> 12, nn = m & 4095, hh = col >> 5;
      const size_t li = ((size_t)(bb * 16 + hh)) * 4096 + nn;
      float inv = 1.f / (Lp[li] + Lp[(size_t)32 * 4096 + li]);
      bf16x8 av;
      av[0] = (__bf16)((x0.x + y0.x) * inv);
      av[1] = (__bf16)((x0.y + y0.y) * inv);
      av[2] = (__bf16)((x0.z + y0.z) * inv);
      av[3] = (__bf16)((x0.w + y0.w) * inv);
      av[4] = (__bf16)((x1.x + y1.x) * inv);
      av[5] = (__bf16)((x1.y + y1.y) * inv);
      av[6] = (__bf16)((x1.z + y1.z) * inv);
      av[7] = (__bf16)((x1.w + y1.w) * inv);
      *reinterpret_cast<bf16x8*>(As + (size_t)c * 8) = av;
      gload16(Bs + (size_t)(it * 256 + w * 64) * 8,
              Bt + (size_t)(n0 + row) * DIMQ + kt + js * 8);
    }
    __syncthreads();
#pragma unroll
    for (int kk = 0; kk < 2; ++kk) {
      bf16x8 a[4], b[4];
#pragma unroll
      for (int mt = 0; mt < 4; ++mt) {
        int row = wr * 64 + mt * 16 + (l & 15);
        int g = (kk * 4 + (l >> 4)) ^ (row & 7);
        a[mt] = *reinterpret_cast<const bf16x8*>((const char*)As + row * 128 + g * 16);
      }
#pragma unroll
      for (int nt = 0; nt < 4; ++nt) {
        int row = wc * 64 + nt * 16 + (l & 15);
        int g = (kk * 4 + (l >> 4)) ^ (row & 7);
        b[nt] = *reinterpret_cast<const bf16x8*>((const char*)Bs + row * 128 + g * 16);
      }
#pragma unroll
      for (int mt = 0; mt < 4; ++mt)
#pragma unroll
        for (int nt = 0; nt < 4; ++nt)
          acc[mt][nt] = __builtin_amdgcn_mfma_f32_16x16x32_bf16(a[mt], b[nt], acc[mt][nt], 0, 0, 0);
    }
  }
#pragma unroll
  for (int nt = 0; nt < 4; ++nt) {
    int n = n0 + wc * 64 + nt * 16 + (l & 15);
#pragma unroll
    for (int mt = 0; mt < 4; ++mt) {
      int m = m0 + wr * 64 + mt * 16 + (l >> 4) * 4;
      f32x4 v = acc[mt][nt];
      float* p = Out + (size_t)m * DIMQ + n;
      p[0] = v[0]; p[DIMQ] = v[1];
      p[2 * DIMQ] = v[2]; p[3 * DIMQ] = v[3];
    }
  }
}

// ---------------- launcher ----------------
extern "C" void kernel_launch(void* const* d_in, const int* in_sizes, int n_in,
                              void* d_out, int out_size, void* d_ws, size_t ws_size,
                              hipStream_t stream) {
  (void)in_sizes; (void)n_in; (void)out_size; (void)ws_size;
  const float* batch  = (const float*)d_in[0];
  const float* w_qkv  = (const float*)d_in[1];
  const float* w_proj = (const float*)d_in[2];
  const int*   cmask  = (const int*)d_in[3];

  __bf16* Abf = (__bf16*)d_ws;                       // 8192*512 bf16      (8 MB)
  __bf16* WqT = Abf + (size_t)8192 * 512;            // 1536*512           (1.5 MB)
  __bf16* WpT = WqT + (size_t)1536 * 512;            // 512*512            (0.5 MB)
  u64*    mb  = (u64*)(WpT + (size_t)512 * 512);     // 4096*64 u64        (2 MB)
  __bf16* Qh  = (__bf16*)(mb + (size_t)4096 * 64);   // 32*4096*32         (8 MB)
  __bf16* Kh  = Qh + (size_t)32 * NSEQ * HDIM;       //                    (8 MB)
  __bf16* VT  = Kh + (size_t)32 * NSEQ * HDIM;       //                    (8 MB)
  float*  Opart = (float*)(VT + (size_t)32 * NSEQ * HDIM); // 2 x 16 MB
  float*  Lpart = Opart + (size_t)2 * 8192 * 512;          // 2 x 0.5 MB

  k_cvt_bf16<<<4096, 256, 0, stream>>>(batch, Abf);
  k_cvtT<<<dim3(24, 8), 256, 0, stream>>>(w_qkv, WqT, 1536);
  k_cvtT<<<dim3(8, 8), 256, 0, stream>>>(w_proj, WpT, 512);
  k_maskbits<<<4096, 256, 0, stream>>>(cmask, mb);
  k_gemm_qkv<<<768, 256, 0, stream>>>(Abf, WqT, Qh, Kh, VT);
  k_attn<<<2048, 256, 0, stream>>>(Qh, Kh, VT, mb, Opart, Lpart);
  k_gemm_proj<<<256, 256, 0, stream>>>(Opart, Lpart, WpT, (float*)d_out);
}